// Round 10
// baseline (377.909 us; speedup 1.0000x reference)
//
#include <hip/hip_runtime.h>
#include <hip/hip_bf16.h>
#include <hip/hip_cooperative_groups.h>
#include <cstdint>

namespace cg = cooperative_groups;

#define D_DIM 128
#define N0_C 50000
#define N1_C 5000
#define E0_C 800000
#define E1_C 80000
#define NB0_C 391      // graph0 bins: 128 dsts each (shift 7)
#define CAP0 2560      // 2048 +/- 45 per bin, 11 sigma headroom
#define NB1_C 157      // N1-space bins: 32 dsts each (shift 5)
#define CAP1 640       // graph1: ~510/bin, +5.8 sigma
#define CAPD 512       // down:   ~318/bin, +10.9 sigma

typedef __attribute__((ext_vector_type(8))) short bf16x8;
typedef __attribute__((ext_vector_type(4))) float f32x4;
typedef __attribute__((ext_vector_type(2))) float f32x2;

__device__ __forceinline__ ushort f2bf_rne(float x) {
    unsigned int u = __float_as_uint(x);
    return (ushort)((u + 0x7FFFu + ((u >> 16) & 1u)) >> 16);
}
__device__ __forceinline__ float bf2f(ushort h) {
    return __uint_as_float(((unsigned int)h) << 16);
}
__device__ __forceinline__ int imin(int a, int b) { return a < b ? a : b; }
__device__ __forceinline__ void online2(float& m, float& s, float mo, float so) {
    if (mo > m) { s = s * __expf(m - mo) + so; m = mo; }
    else s += so * __expf(mo - m);
}
__device__ __forceinline__ void acc8_add_bf(float* acc, uint4 r) {
    acc[0] += __uint_as_float(r.x << 16);
    acc[1] += __uint_as_float(r.x & 0xFFFF0000u);
    acc[2] += __uint_as_float(r.y << 16);
    acc[3] += __uint_as_float(r.y & 0xFFFF0000u);
    acc[4] += __uint_as_float(r.z << 16);
    acc[5] += __uint_as_float(r.z & 0xFFFF0000u);
    acc[6] += __uint_as_float(r.w << 16);
    acc[7] += __uint_as_float(r.w & 0xFFFF0000u);
}
__device__ __forceinline__ void acc8_add_f8(float* acc, uint2 r) {
    f32x2 a = __builtin_amdgcn_cvt_pk_f32_fp8((int)r.x, false);
    f32x2 b = __builtin_amdgcn_cvt_pk_f32_fp8((int)r.x, true);
    f32x2 c = __builtin_amdgcn_cvt_pk_f32_fp8((int)r.y, false);
    f32x2 d = __builtin_amdgcn_cvt_pk_f32_fp8((int)r.y, true);
    acc[0] += a[0]; acc[1] += a[1]; acc[2] += b[0]; acc[3] += b[1];
    acc[4] += c[0]; acc[5] += c[1]; acc[6] += d[0]; acc[7] += d[1];
}

// ---------------------------------------------------------------------------
// weight prep + counter zeroing (memset launch folded in as block 512).
// wt mats 0:W0s 1:W0n 2:W1s 3:W1n 4:W2s_top 5:W2s_bot 6:W2n_top 7:W2n_bot,
// stored col-major bf16 (n*128 + k).
// ---------------------------------------------------------------------------
__global__ __launch_bounds__(256) void wtprep_kernel(
    const float* __restrict__ W0s, const float* __restrict__ W0n,
    const float* __restrict__ W1s, const float* __restrict__ W1n,
    const float* __restrict__ W2s, const float* __restrict__ W2n,
    ushort* __restrict__ wt, int* __restrict__ zr) {
    if (blockIdx.x >= 512) {
        #pragma unroll
        for (int i = 0; i < 4; ++i) zr[threadIdx.x + i * 256] = 0;
        return;
    }
    int gi = blockIdx.x * 256 + threadIdx.x;
    int mi = gi >> 14, idx = gi & 16383;
    int k = idx >> 7, n = idx & 127;
    const float* src; int row = k;
    switch (mi) {
        case 0: src = W0s; break;
        case 1: src = W0n; break;
        case 2: src = W1s; break;
        case 3: src = W1n; break;
        case 4: src = W2s; break;
        case 5: src = W2s; row = k + 128; break;
        case 6: src = W2n; break;
        default: src = W2n; row = k + 128; break;
    }
    wt[(mi << 14) + n * 128 + k] = f2bf_rne(src[row * 128 + n]);
}

// ---------------------------------------------------------------------------
// scatgemm: binned pair-scatter for all three edge sets (4096 edges/block)
// + layer-0 dual GEMM with next-tile A-prefetch.
// pair key = (local_dst << 17) | src   (src < 2^17, local < 128)
// ---------------------------------------------------------------------------
__global__ __launch_bounds__(256, 2) void scatgemm_kernel(
    const int* __restrict__ src0, const int* __restrict__ dst0,
    const int* __restrict__ src1, const int* __restrict__ dst1,
    const int* __restrict__ dsrc, const int* __restrict__ ddst,
    int* __restrict__ bincur0, int* __restrict__ bincur1, int* __restrict__ bincurD,
    int* __restrict__ pairs0, int* __restrict__ pairs1, int* __restrict__ pairsD,
    int nb0, int nb1, int nbd,
    const float* __restrict__ A,
    const ushort* __restrict__ w1, const ushort* __restrict__ w2,
    const float* __restrict__ bias1,
    ushort* __restrict__ O1b, unsigned char* __restrict__ O2f8,
    int N, int ntiles) {
    __shared__ int lcnt[512];
    __shared__ int sbase[512];
    const int b = blockIdx.x, t = threadIdx.x;
    const int nscat = nb0 + nb1 + nbd;
    if (b < nscat) {
        const int* srcp; const int* dstp; int* bc; int* pr;
        int e0, emax, shift, cap, nbins;
        if (b < nb0) {
            srcp = src0; dstp = dst0; bc = bincur0; pr = pairs0;
            e0 = b * 4096; emax = E0_C; shift = 7; cap = CAP0; nbins = NB0_C;
        } else if (b < nb0 + nb1) {
            srcp = src1; dstp = dst1; bc = bincur1; pr = pairs1;
            e0 = (b - nb0) * 4096; emax = E1_C; shift = 5; cap = CAP1; nbins = NB1_C;
        } else {
            srcp = dsrc; dstp = ddst; bc = bincurD; pr = pairsD;
            e0 = (b - nb0 - nb1) * 4096; emax = N0_C; shift = 5; cap = CAPD; nbins = NB1_C;
        }
        const int mask = (1 << shift) - 1;
        for (int i = t; i < 512; i += 256) lcnt[i] = 0;
        __syncthreads();
        int lrank[16], dloc[16];
        #pragma unroll
        for (int i = 0; i < 16; ++i) {
            int e = e0 + t + i * 256;
            if (e < emax) {
                int d = dstp[e];
                dloc[i] = d;
                lrank[i] = atomicAdd(&lcnt[d >> shift], 1);
            } else dloc[i] = -1;
        }
        __syncthreads();
        for (int i = t; i < nbins; i += 256)
            if (lcnt[i] > 0) sbase[i] = atomicAdd(&bc[i], lcnt[i]);
        __syncthreads();
        #pragma unroll
        for (int i = 0; i < 16; ++i) {
            int e = e0 + t + i * 256;
            if (e < emax) {
                int d = dloc[i];
                int bin = d >> shift;
                int key = ((d & mask) << 17) | srcp[e];
                pr[(size_t)bin * cap + sbase[bin] + lrank[i]] = key;
            }
        }
        return;
    }
    // ---- layer-0 dual GEMM (swapped operands; next-tile A prefetch) ----
    const int gstride = gridDim.x - nscat;
    const int bid = b - nscat;
    const int wave = t >> 6, lane = t & 63;
    const int m = lane & 15, quad = lane >> 4;
    const int colbase = wave * 32;
    bf16x8 bf[4][2][2];
    #pragma unroll
    for (int c = 0; c < 4; ++c)
        #pragma unroll
        for (int ct = 0; ct < 2; ++ct) {
            const size_t bo = (size_t)(colbase + ct * 16 + m) * 128 + c * 32 + quad * 8;
            bf[c][ct][0] = *(const bf16x8*)(w1 + bo);
            bf[c][ct][1] = *(const bf16x8*)(w2 + bo);
        }
    const f32x4 zero = {0.f, 0.f, 0.f, 0.f};
    float4 pa0[4], pa1[4];
    auto ldA = [&](int tile) {
        const int r0 = tile * 16;
        int ar = r0 + m; if (ar >= N) ar = N - 1;
        const float* arow = A + (size_t)ar * 128;
        #pragma unroll
        for (int c = 0; c < 4; ++c) {
            pa0[c] = *(const float4*)(arow + c * 32 + quad * 8);
            pa1[c] = *(const float4*)(arow + c * 32 + quad * 8 + 4);
        }
    };
    if (bid < ntiles) ldA(bid);
    for (int tile = bid; tile < ntiles; tile += gstride) {
        float4 ca0[4], ca1[4];
        #pragma unroll
        for (int c = 0; c < 4; ++c) { ca0[c] = pa0[c]; ca1[c] = pa1[c]; }
        const int nxt = tile + gstride;
        if (nxt < ntiles) ldA(nxt);          // issue next-tile loads early
        f32x4 acc[2][2];
        acc[0][0] = zero; acc[0][1] = zero; acc[1][0] = zero; acc[1][1] = zero;
        #pragma unroll
        for (int c = 0; c < 4; ++c) {
            float av[8] = {ca0[c].x, ca0[c].y, ca0[c].z, ca0[c].w,
                           ca1[c].x, ca1[c].y, ca1[c].z, ca1[c].w};
            bf16x8 afh, afl;
            #pragma unroll
            for (int i = 0; i < 8; ++i) {
                ushort h = f2bf_rne(av[i]);
                ushort l = f2bf_rne(av[i] - bf2f(h));
                afh[i] = (short)h; afl[i] = (short)l;
            }
            #pragma unroll
            for (int ct = 0; ct < 2; ++ct) {
                acc[ct][0] = __builtin_amdgcn_mfma_f32_16x16x32_bf16(bf[c][ct][0], afh, acc[ct][0], 0, 0, 0);
                acc[ct][0] = __builtin_amdgcn_mfma_f32_16x16x32_bf16(bf[c][ct][0], afl, acc[ct][0], 0, 0, 0);
                acc[ct][1] = __builtin_amdgcn_mfma_f32_16x16x32_bf16(bf[c][ct][1], afh, acc[ct][1], 0, 0, 0);
                acc[ct][1] = __builtin_amdgcn_mfma_f32_16x16x32_bf16(bf[c][ct][1], afl, acc[ct][1], 0, 0, 0);
            }
        }
        const int r = tile * 16 + m;
        #pragma unroll
        for (int ct = 0; ct < 2; ++ct) {
            const int wc = colbase + ct * 16 + quad * 4;
            float4 bv = bias1 ? *(const float4*)&bias1[wc] : make_float4(0.f, 0.f, 0.f, 0.f);
            float o1[4], o2[4];
            o1[0] = acc[ct][0][0] + bv.x; o1[1] = acc[ct][0][1] + bv.y;
            o1[2] = acc[ct][0][2] + bv.z; o1[3] = acc[ct][0][3] + bv.w;
            o2[0] = acc[ct][1][0]; o2[1] = acc[ct][1][1];
            o2[2] = acc[ct][1][2]; o2[3] = acc[ct][1][3];
            if (r < N) {
                uint2 u;
                u.x = (uint)f2bf_rne(o1[0]) | ((uint)f2bf_rne(o1[1]) << 16);
                u.y = (uint)f2bf_rne(o1[2]) | ((uint)f2bf_rne(o1[3]) << 16);
                *(uint2*)&O1b[(size_t)r * D_DIM + wc] = u;
                int pk = __builtin_amdgcn_cvt_pk_fp8_f32(o2[0], o2[1], 0, false);
                pk = __builtin_amdgcn_cvt_pk_fp8_f32(o2[2], o2[3], pk, true);
                *(uint*)&O2f8[(size_t)r * D_DIM + wc] = (uint)pk;
            }
        }
    }
}

// ---------------------------------------------------------------------------
// sortbins: one block per bin (all three edge sets). In-LDS rank + scan ->
// sorted colv written back to GLOBAL (coalesced) + per-dst beg/end arrays.
// ---------------------------------------------------------------------------
__global__ __launch_bounds__(256) void sortbins_kernel(
    const int* __restrict__ pairs0, const int* __restrict__ bincur0,
    const int* __restrict__ pairs1, const int* __restrict__ bincur1,
    const int* __restrict__ pairsD, const int* __restrict__ bincurD,
    int* __restrict__ col0, int* __restrict__ beg0, int* __restrict__ end0,
    int* __restrict__ col1, int* __restrict__ beg1, int* __restrict__ end1,
    int* __restrict__ colD, int* __restrict__ begD, int* __restrict__ endD) {
    __shared__ int cols[CAP0];
    __shared__ int cur[128];
    __shared__ int wtot_s;
    const int tid = threadIdx.x;
    int b = blockIdx.x;
    const int* pr; const int* bc; int* cg; int* bg; int* eg;
    int cap, nloc, nbase, nmax;
    if (b < NB0_C) {
        pr = pairs0; bc = bincur0; cg = col0; bg = beg0; eg = end0;
        cap = CAP0; nloc = 128; nbase = b << 7; nmax = N0_C;
    } else if (b < NB0_C + NB1_C) {
        b -= NB0_C;
        pr = pairs1; bc = bincur1; cg = col1; bg = beg1; eg = end1;
        cap = CAP1; nloc = 32; nbase = b << 5; nmax = N1_C;
    } else {
        b -= NB0_C + NB1_C;
        pr = pairsD; bc = bincurD; cg = colD; bg = begD; eg = endD;
        cap = CAPD; nloc = 32; nbase = b << 5; nmax = N1_C;
    }
    const size_t base = (size_t)b * cap;
    int cnt = bc[b]; if (cnt > cap) cnt = cap;
    if (tid < 128) cur[tid] = 0;
    __syncthreads();
    int key[10], rank[10];
    #pragma unroll
    for (int k = 0; k < 10; ++k) {
        int idx = tid + k * 256;
        key[k] = (idx < cnt) ? pr[base + idx] : -1;
    }
    #pragma unroll
    for (int k = 0; k < 10; ++k)
        if (key[k] >= 0) rank[k] = atomicAdd(&cur[key[k] >> 17], 1);
    __syncthreads();
    __shared__ int rp[129];
    int v = 0, x = 0;
    if (tid < 128) {
        v = cur[tid];
        x = v;
        int lane = tid & 63;
        #pragma unroll
        for (int off = 1; off < 64; off <<= 1) {
            int y = __shfl_up(x, off);
            if (lane >= off) x += y;
        }
        if (tid == 63) wtot_s = x;
    }
    __syncthreads();
    if (tid < 128) {
        int excl = x - v + ((tid >= 64) ? wtot_s : 0);
        rp[tid] = excl;
        if (tid == 127) rp[128] = excl + v;
        if (tid < nloc) {
            int n = nbase + tid;
            if (n < nmax) {
                bg[n] = (int)base + excl;
                eg[n] = (int)base + excl + v;
            }
        }
    }
    __syncthreads();
    #pragma unroll
    for (int k = 0; k < 10; ++k)
        if (key[k] >= 0)
            cols[rp[key[k] >> 17] + rank[k]] = key[k] & 0x1FFFF;
    __syncthreads();
    for (int i = tid; i < cnt; i += 256) cg[base + i] = cols[i];
}

// ---------------------------------------------------------------------------
// big CSR gather-aggregate, 2 nodes/wave; FP8 (128B rows) or bf16 (256B rows).
// Optional bf16 addvb OR f32 addvf; out bf16 outb OR f32 outf OR fused
// readout z = (...)@Wm + bm with per-block online-softmax partial to redp.
// ---------------------------------------------------------------------------
template <int FP8>
__global__ __launch_bounds__(256) void csr_agg_big(
    const void* __restrict__ featv,
    const int* __restrict__ rpbeg, const int* __restrict__ rpend,
    const int* __restrict__ colv,
    const ushort* __restrict__ addvb, const float* __restrict__ addvf,
    const float* __restrict__ bias,
    ushort* __restrict__ outb, float* __restrict__ outf,
    const float* __restrict__ Wm, const float* __restrict__ bm,
    float* __restrict__ z, float* __restrict__ redp, int Ndst, int do_relu) {
    __shared__ float zsh[8];
    const char* feat = (const char*)featv;
    int gt = blockIdx.x * blockDim.x + threadIdx.x;
    int wp = gt >> 6;
    int nA = wp * 2;
    if (nA >= Ndst) return;
    int nB = nA + 1;
    bool hasB = (nB < Ndst);
    int lane = threadIdx.x & 63;
    int q = lane >> 4, li = lane & 15;
    float accA[8], accB[8];
    #pragma unroll
    for (int i = 0; i < 8; ++i) { accA[i] = 0.f; accB[i] = 0.f; }
    int begA = rpbeg[nA], endA = rpend[nA];
    int begB = 0, endB = 0;
    if (hasB) { begB = rpbeg[nB]; endB = rpend[nB]; }
    int degA = endA - begA, degB = endB - begB;
    int lastA = (degA > 0) ? endA - 1 : 0;
    int lastB = (degB > 0) ? endB - 1 : 0;
    int jA = begA + q, jB = begB + q;
    while (jA < endA || jB < endB) {
        int ia[4], ib[4];
        #pragma unroll
        for (int k = 0; k < 4; ++k) {
            ia[k] = imin(jA + 4 * k, lastA);
            ib[k] = imin(jB + 4 * k, lastB);
        }
        if (FP8) {
            uint2 va[4], vb[4];
            #pragma unroll
            for (int k = 0; k < 4; ++k) {
                int ra = colv[ia[k]];
                va[k] = *(const uint2*)(feat + (size_t)ra * 128 + li * 8);
            }
            #pragma unroll
            for (int k = 0; k < 4; ++k) {
                int rb = colv[ib[k]];
                vb[k] = *(const uint2*)(feat + (size_t)rb * 128 + li * 8);
            }
            #pragma unroll
            for (int k = 0; k < 4; ++k) {
                if (jA + 4 * k < endA) acc8_add_f8(accA, va[k]);
                if (jB + 4 * k < endB) acc8_add_f8(accB, vb[k]);
            }
        } else {
            uint4 va[4], vb[4];
            #pragma unroll
            for (int k = 0; k < 4; ++k) {
                int ra = colv[ia[k]];
                va[k] = *(const uint4*)(feat + (size_t)ra * 256 + li * 16);
            }
            #pragma unroll
            for (int k = 0; k < 4; ++k) {
                int rb = colv[ib[k]];
                vb[k] = *(const uint4*)(feat + (size_t)rb * 256 + li * 16);
            }
            #pragma unroll
            for (int k = 0; k < 4; ++k) {
                if (jA + 4 * k < endA) acc8_add_bf(accA, va[k]);
                if (jB + 4 * k < endB) acc8_add_bf(accB, vb[k]);
            }
        }
        jA += 16; jB += 16;
    }
    const int f8 = li * 8;
    #pragma unroll
    for (int i = 0; i < 8; ++i) {
        accA[i] += __shfl_xor(accA[i], 16);
        accA[i] += __shfl_xor(accA[i], 32);
        accB[i] += __shfl_xor(accB[i], 16);
        accB[i] += __shfl_xor(accB[i], 32);
    }
    float invA = 1.f / fmaxf((float)degA, 1.f);
    float invB = 1.f / fmaxf((float)degB, 1.f);
    #pragma unroll
    for (int i = 0; i < 8; ++i) { accA[i] *= invA; accB[i] *= invB; }
    if (addvb) {
        uint4 a = *(const uint4*)&addvb[(size_t)nA * D_DIM + f8];
        acc8_add_bf(accA, a);
        if (hasB) {
            uint4 b = *(const uint4*)&addvb[(size_t)nB * D_DIM + f8];
            acc8_add_bf(accB, b);
        }
    }
    if (addvf) {
        float4 g0 = *(const float4*)&addvf[(size_t)nA * D_DIM + f8];
        float4 g1 = *(const float4*)&addvf[(size_t)nA * D_DIM + f8 + 4];
        accA[0] += g0.x; accA[1] += g0.y; accA[2] += g0.z; accA[3] += g0.w;
        accA[4] += g1.x; accA[5] += g1.y; accA[6] += g1.z; accA[7] += g1.w;
        if (hasB) {
            float4 h0 = *(const float4*)&addvf[(size_t)nB * D_DIM + f8];
            float4 h1 = *(const float4*)&addvf[(size_t)nB * D_DIM + f8 + 4];
            accB[0] += h0.x; accB[1] += h0.y; accB[2] += h0.z; accB[3] += h0.w;
            accB[4] += h1.x; accB[5] += h1.y; accB[6] += h1.z; accB[7] += h1.w;
        }
    }
    if (bias) {
        float4 b0 = *(const float4*)&bias[f8];
        float4 b1 = *(const float4*)&bias[f8 + 4];
        accA[0] += b0.x; accA[1] += b0.y; accA[2] += b0.z; accA[3] += b0.w;
        accA[4] += b1.x; accA[5] += b1.y; accA[6] += b1.z; accA[7] += b1.w;
        accB[0] += b0.x; accB[1] += b0.y; accB[2] += b0.z; accB[3] += b0.w;
        accB[4] += b1.x; accB[5] += b1.y; accB[6] += b1.z; accB[7] += b1.w;
    }
    if (do_relu) {
        #pragma unroll
        for (int i = 0; i < 8; ++i) {
            accA[i] = fmaxf(accA[i], 0.f);
            accB[i] = fmaxf(accB[i], 0.f);
        }
    }
    if (outb) {
        if (q == 0) {
            uint4 o;
            o.x = (uint)f2bf_rne(accA[0]) | ((uint)f2bf_rne(accA[1]) << 16);
            o.y = (uint)f2bf_rne(accA[2]) | ((uint)f2bf_rne(accA[3]) << 16);
            o.z = (uint)f2bf_rne(accA[4]) | ((uint)f2bf_rne(accA[5]) << 16);
            o.w = (uint)f2bf_rne(accA[6]) | ((uint)f2bf_rne(accA[7]) << 16);
            *(uint4*)&outb[(size_t)nA * D_DIM + f8] = o;
        } else if (q == 1 && hasB) {
            uint4 o;
            o.x = (uint)f2bf_rne(accB[0]) | ((uint)f2bf_rne(accB[1]) << 16);
            o.y = (uint)f2bf_rne(accB[2]) | ((uint)f2bf_rne(accB[3]) << 16);
            o.z = (uint)f2bf_rne(accB[4]) | ((uint)f2bf_rne(accB[5]) << 16);
            o.w = (uint)f2bf_rne(accB[6]) | ((uint)f2bf_rne(accB[7]) << 16);
            *(uint4*)&outb[(size_t)nB * D_DIM + f8] = o;
        }
    } else if (outf) {
        if (q == 0) {
            float4 s0, s1;
            s0.x = accA[0]; s0.y = accA[1]; s0.z = accA[2]; s0.w = accA[3];
            s1.x = accA[4]; s1.y = accA[5]; s1.z = accA[6]; s1.w = accA[7];
            *(float4*)&outf[(size_t)nA * D_DIM + f8] = s0;
            *(float4*)&outf[(size_t)nA * D_DIM + f8 + 4] = s1;
        } else if (q == 1 && hasB) {
            float4 s0, s1;
            s0.x = accB[0]; s0.y = accB[1]; s0.z = accB[2]; s0.w = accB[3];
            s1.x = accB[4]; s1.y = accB[5]; s1.z = accB[6]; s1.w = accB[7];
            *(float4*)&outf[(size_t)nB * D_DIM + f8] = s0;
            *(float4*)&outf[(size_t)nB * D_DIM + f8 + 4] = s1;
        }
    }
    if (z) {
        float4 w0 = *(const float4*)&Wm[f8];
        float4 w1 = *(const float4*)&Wm[f8 + 4];
        float p = 0.f;
        if (q == 0)
            p = accA[0] * w0.x + accA[1] * w0.y + accA[2] * w0.z + accA[3] * w0.w
              + accA[4] * w1.x + accA[5] * w1.y + accA[6] * w1.z + accA[7] * w1.w;
        else if (q == 1)
            p = accB[0] * w0.x + accB[1] * w0.y + accB[2] * w0.z + accB[3] * w0.w
              + accB[4] * w1.x + accB[5] * w1.y + accB[6] * w1.z + accB[7] * w1.w;
        #pragma unroll
        for (int off = 8; off > 0; off >>= 1) p += __shfl_down(p, off);
        const int wv = threadIdx.x >> 6;
        if (lane == 0) {
            float zv = p + bm[0];
            z[nA] = zv;
            if (redp) zsh[2 * wv] = zv;
        }
        if (lane == 16 && hasB) {
            float zv = p + bm[0];
            z[nB] = zv;
            if (redp) zsh[2 * wv + 1] = zv;
        }
        if (redp) {
            // exact grid sizing for the readout launch: all 8 slots written.
            __syncthreads();
            if (threadIdx.x == 0) {
                float m = -1e30f, s = 0.f;
                #pragma unroll
                for (int i = 0; i < 8; ++i) {
                    float v = zsh[i];
                    if (v > m) { s = s * __expf(m - v) + 1.f; m = v; }
                    else s += __expf(v - m);
                }
                redp[2 * blockIdx.x] = m;
                redp[2 * blockIdx.x + 1] = s;
            }
        }
    }
}

// ---------------------------------------------------------------------------
// device helpers for the cooperative N1 chain (no LDS, no early returns).
// ---------------------------------------------------------------------------
// bf16-row gather, 2 nodes/wave, grid-stride; optional f32 addv; bf16 or f32 out
__device__ void dev_agg_n1(
    const ushort* __restrict__ feat,
    const int* __restrict__ rpbeg, const int* __restrict__ rpend,
    const int* __restrict__ colv, const float* __restrict__ addvf,
    ushort* __restrict__ outb, float* __restrict__ outf, int Ndst, int do_relu) {
    const int nwav = (gridDim.x * blockDim.x) >> 6;
    const int gw0 = (blockIdx.x * blockDim.x + threadIdx.x) >> 6;
    const int lane = threadIdx.x & 63;
    const int q = lane >> 4, li = lane & 15;
    const int f8 = li * 8;
    for (int wp = gw0; wp * 2 < Ndst; wp += nwav) {
        const int nA = wp * 2, nB = nA + 1;
        const bool hasB = (nB < Ndst);
        float accA[8], accB[8];
        #pragma unroll
        for (int i = 0; i < 8; ++i) { accA[i] = 0.f; accB[i] = 0.f; }
        int begA = rpbeg[nA], endA = rpend[nA];
        int begB = 0, endB = 0;
        if (hasB) { begB = rpbeg[nB]; endB = rpend[nB]; }
        int degA = endA - begA, degB = endB - begB;
        int lastA = (degA > 0) ? endA - 1 : 0;
        int lastB = (degB > 0) ? endB - 1 : 0;
        int jA = begA + q, jB = begB + q;
        while (jA < endA || jB < endB) {
            int ia[4], ib[4];
            #pragma unroll
            for (int k = 0; k < 4; ++k) {
                ia[k] = imin(jA + 4 * k, lastA);
                ib[k] = imin(jB + 4 * k, lastB);
            }
            uint4 va[4], vb[4];
            #pragma unroll
            for (int k = 0; k < 4; ++k) {
                int ra = colv[ia[k]];
                va[k] = *(const uint4*)(feat + (size_t)ra * D_DIM + li * 8);
            }
            #pragma unroll
            for (int k = 0; k < 4; ++k) {
                int rb = colv[ib[k]];
                vb[k] = *(const uint4*)(feat + (size_t)rb * D_DIM + li * 8);
            }
            #pragma unroll
            for (int k = 0; k < 4; ++k) {
                if (jA + 4 * k < endA) acc8_add_bf(accA, va[k]);
                if (jB + 4 * k < endB) acc8_add_bf(accB, vb[k]);
            }
            jA += 16; jB += 16;
        }
        #pragma unroll
        for (int i = 0; i < 8; ++i) {
            accA[i] += __shfl_xor(accA[i], 16);
            accA[i] += __shfl_xor(accA[i], 32);
            accB[i] += __shfl_xor(accB[i], 16);
            accB[i] += __shfl_xor(accB[i], 32);
        }
        float invA = 1.f / fmaxf((float)degA, 1.f);
        float invB = 1.f / fmaxf((float)degB, 1.f);
        #pragma unroll
        for (int i = 0; i < 8; ++i) { accA[i] *= invA; accB[i] *= invB; }
        if (addvf) {
            float4 g0 = *(const float4*)&addvf[(size_t)nA * D_DIM + f8];
            float4 g1 = *(const float4*)&addvf[(size_t)nA * D_DIM + f8 + 4];
            accA[0] += g0.x; accA[1] += g0.y; accA[2] += g0.z; accA[3] += g0.w;
            accA[4] += g1.x; accA[5] += g1.y; accA[6] += g1.z; accA[7] += g1.w;
            if (hasB) {
                float4 h0 = *(const float4*)&addvf[(size_t)nB * D_DIM + f8];
                float4 h1 = *(const float4*)&addvf[(size_t)nB * D_DIM + f8 + 4];
                accB[0] += h0.x; accB[1] += h0.y; accB[2] += h0.z; accB[3] += h0.w;
                accB[4] += h1.x; accB[5] += h1.y; accB[6] += h1.z; accB[7] += h1.w;
            }
        }
        if (do_relu) {
            #pragma unroll
            for (int i = 0; i < 8; ++i) {
                accA[i] = fmaxf(accA[i], 0.f);
                accB[i] = fmaxf(accB[i], 0.f);
            }
        }
        if (outb) {
            if (q == 0) {
                uint4 o;
                o.x = (uint)f2bf_rne(accA[0]) | ((uint)f2bf_rne(accA[1]) << 16);
                o.y = (uint)f2bf_rne(accA[2]) | ((uint)f2bf_rne(accA[3]) << 16);
                o.z = (uint)f2bf_rne(accA[4]) | ((uint)f2bf_rne(accA[5]) << 16);
                o.w = (uint)f2bf_rne(accA[6]) | ((uint)f2bf_rne(accA[7]) << 16);
                *(uint4*)&outb[(size_t)nA * D_DIM + f8] = o;
            } else if (q == 1 && hasB) {
                uint4 o;
                o.x = (uint)f2bf_rne(accB[0]) | ((uint)f2bf_rne(accB[1]) << 16);
                o.y = (uint)f2bf_rne(accB[2]) | ((uint)f2bf_rne(accB[3]) << 16);
                o.z = (uint)f2bf_rne(accB[4]) | ((uint)f2bf_rne(accB[5]) << 16);
                o.w = (uint)f2bf_rne(accB[6]) | ((uint)f2bf_rne(accB[7]) << 16);
                *(uint4*)&outb[(size_t)nB * D_DIM + f8] = o;
            }
        } else {
            if (q == 0) {
                float4 s0, s1;
                s0.x = accA[0]; s0.y = accA[1]; s0.z = accA[2]; s0.w = accA[3];
                s1.x = accA[4]; s1.y = accA[5]; s1.z = accA[6]; s1.w = accA[7];
                *(float4*)&outf[(size_t)nA * D_DIM + f8] = s0;
                *(float4*)&outf[(size_t)nA * D_DIM + f8 + 4] = s1;
            } else if (q == 1 && hasB) {
                float4 s0, s1;
                s0.x = accB[0]; s0.y = accB[1]; s0.z = accB[2]; s0.w = accB[3];
                s1.x = accB[4]; s1.y = accB[5]; s1.z = accB[6]; s1.w = accB[7];
                *(float4*)&outf[(size_t)nB * D_DIM + f8] = s0;
                *(float4*)&outf[(size_t)nB * D_DIM + f8 + 4] = s1;
            }
        }
    }
}

// bf16-A dual GEMM: f32 O1 (+bias) + bf16 O2, grid-stride tiles
__device__ void dev_mm_b(
    const ushort* __restrict__ Ab,
    const ushort* __restrict__ w1, const ushort* __restrict__ w2,
    const float* __restrict__ bias1,
    float* __restrict__ O1f, ushort* __restrict__ O2bb, int N, int ntiles) {
    const int tid = threadIdx.x;
    const int wave = tid >> 6, lane = tid & 63;
    const int m = lane & 15, quad = lane >> 4;
    const int colbase = wave * 32;
    bf16x8 bf[4][2][2];
    #pragma unroll
    for (int c = 0; c < 4; ++c)
        #pragma unroll
        for (int ct = 0; ct < 2; ++ct) {
            const size_t bo = (size_t)(colbase + ct * 16 + m) * 128 + c * 32 + quad * 8;
            bf[c][ct][0] = *(const bf16x8*)(w1 + bo);
            bf[c][ct][1] = *(const bf16x8*)(w2 + bo);
        }
    const f32x4 zero = {0.f, 0.f, 0.f, 0.f};
    for (int tile = blockIdx.x; tile < ntiles; tile += gridDim.x) {
        const int r0 = tile * 16;
        int ar = r0 + m; if (ar >= N) ar = N - 1;
        const ushort* arow = Ab + (size_t)ar * 128;
        f32x4 acc[2][2];
        acc[0][0] = zero; acc[0][1] = zero; acc[1][0] = zero; acc[1][1] = zero;
        #pragma unroll
        for (int c = 0; c < 4; ++c) {
            bf16x8 af = *(const bf16x8*)(arow + c * 32 + quad * 8);
            #pragma unroll
            for (int ct = 0; ct < 2; ++ct) {
                acc[ct][0] = __builtin_amdgcn_mfma_f32_16x16x32_bf16(bf[c][ct][0], af, acc[ct][0], 0, 0, 0);
                acc[ct][1] = __builtin_amdgcn_mfma_f32_16x16x32_bf16(bf[c][ct][1], af, acc[ct][1], 0, 0, 0);
            }
        }
        const int r = r0 + m;
        if (r < N) {
            #pragma unroll
            for (int ct = 0; ct < 2; ++ct) {
                const int wc = colbase + ct * 16 + quad * 4;
                float4 bv = bias1 ? *(const float4*)&bias1[wc] : make_float4(0.f, 0.f, 0.f, 0.f);
                float4 s1;
                s1.x = acc[ct][0][0] + bv.x; s1.y = acc[ct][0][1] + bv.y;
                s1.z = acc[ct][0][2] + bv.z; s1.w = acc[ct][0][3] + bv.w;
                *(float4*)&O1f[(size_t)r * D_DIM + wc] = s1;
                uint2 u;
                u.x = (uint)f2bf_rne(acc[ct][1][0]) | ((uint)f2bf_rne(acc[ct][1][1]) << 16);
                u.y = (uint)f2bf_rne(acc[ct][1][2]) | ((uint)f2bf_rne(acc[ct][1][3]) << 16);
                *(uint2*)&O2bb[(size_t)r * D_DIM + wc] = u;
            }
        }
    }
}

// fp32-A dual GEMM (hi/lo split): f32 + f32 outs, grid-stride tiles
__device__ void dev_mm_f(
    const float* __restrict__ A,
    const ushort* __restrict__ w1, const ushort* __restrict__ w2,
    float* __restrict__ O1f, float* __restrict__ O2f, int N, int ntiles) {
    const int tid = threadIdx.x;
    const int wave = tid >> 6, lane = tid & 63;
    const int m = lane & 15, quad = lane >> 4;
    const int colbase = wave * 32;
    bf16x8 bf[4][2][2];
    #pragma unroll
    for (int c = 0; c < 4; ++c)
        #pragma unroll
        for (int ct = 0; ct < 2; ++ct) {
            const size_t bo = (size_t)(colbase + ct * 16 + m) * 128 + c * 32 + quad * 8;
            bf[c][ct][0] = *(const bf16x8*)(w1 + bo);
            bf[c][ct][1] = *(const bf16x8*)(w2 + bo);
        }
    const f32x4 zero = {0.f, 0.f, 0.f, 0.f};
    for (int tile = blockIdx.x; tile < ntiles; tile += gridDim.x) {
        const int r0 = tile * 16;
        int ar = r0 + m; if (ar >= N) ar = N - 1;
        const float* arow = A + (size_t)ar * 128;
        f32x4 acc[2][2];
        acc[0][0] = zero; acc[0][1] = zero; acc[1][0] = zero; acc[1][1] = zero;
        #pragma unroll
        for (int c = 0; c < 4; ++c) {
            float4 a0 = *(const float4*)(arow + c * 32 + quad * 8);
            float4 a1 = *(const float4*)(arow + c * 32 + quad * 8 + 4);
            float av[8] = {a0.x, a0.y, a0.z, a0.w, a1.x, a1.y, a1.z, a1.w};
            bf16x8 afh, afl;
            #pragma unroll
            for (int i = 0; i < 8; ++i) {
                ushort h = f2bf_rne(av[i]);
                ushort l = f2bf_rne(av[i] - bf2f(h));
                afh[i] = (short)h; afl[i] = (short)l;
            }
            #pragma unroll
            for (int ct = 0; ct < 2; ++ct) {
                acc[ct][0] = __builtin_amdgcn_mfma_f32_16x16x32_bf16(bf[c][ct][0], afh, acc[ct][0], 0, 0, 0);
                acc[ct][0] = __builtin_amdgcn_mfma_f32_16x16x32_bf16(bf[c][ct][0], afl, acc[ct][0], 0, 0, 0);
                acc[ct][1] = __builtin_amdgcn_mfma_f32_16x16x32_bf16(bf[c][ct][1], afh, acc[ct][1], 0, 0, 0);
                acc[ct][1] = __builtin_amdgcn_mfma_f32_16x16x32_bf16(bf[c][ct][1], afl, acc[ct][1], 0, 0, 0);
            }
        }
        const int r = r0 + m;
        if (r < N) {
            #pragma unroll
            for (int ct = 0; ct < 2; ++ct) {
                const int wc = colbase + ct * 16 + quad * 4;
                float4 s1, s2;
                s1.x = acc[ct][0][0]; s1.y = acc[ct][0][1];
                s1.z = acc[ct][0][2]; s1.w = acc[ct][0][3];
                s2.x = acc[ct][1][0]; s2.y = acc[ct][1][1];
                s2.z = acc[ct][1][2]; s2.w = acc[ct][1][3];
                *(float4*)&O1f[(size_t)r * D_DIM + wc] = s1;
                *(float4*)&O2f[(size_t)r * D_DIM + wc] = s2;
            }
        }
    }
}

// ---------------------------------------------------------------------------
// cooperative N1 chain: down-pool -> mm1 -> graph1 agg -> mm2small, with
// grid.sync() between stages. Replaces 4 launches (+3 launch gaps).
// 256 blocks @ launch_bounds(256,2): co-residency guaranteed (cap >= 512).
// ---------------------------------------------------------------------------
__global__ __launch_bounds__(256, 2) void coop_n1_kernel(
    const ushort* __restrict__ x0b,
    const int* __restrict__ begD, const int* __restrict__ endD,
    const int* __restrict__ colD, ushort* __restrict__ x1bb,
    const ushort* __restrict__ w1s, const ushort* __restrict__ w1n,
    const float* __restrict__ b1, float* __restrict__ y1s, ushort* __restrict__ y1nb,
    const int* __restrict__ beg1, const int* __restrict__ end1,
    const int* __restrict__ col1, float* __restrict__ x1f,
    const ushort* __restrict__ w2t, const ushort* __restrict__ w2nt,
    float* __restrict__ C2, float* __restrict__ D2,
    int N1v, int nt1v) {
    cg::grid_group grid = cg::this_grid();
    // x1 = relu(mean_cluster(x0))
    dev_agg_n1(x0b, begD, endD, colD, nullptr, x1bb, nullptr, N1v, 1);
    grid.sync();
    // y1s = x1@W1s + b1 (f32), y1n = x1@W1n (bf16)
    dev_mm_b(x1bb, w1s, w1n, b1, y1s, y1nb, N1v, nt1v);
    grid.sync();
    // x1f = relu(y1s + mean_nbr(y1n))
    dev_agg_n1(y1nb, beg1, end1, col1, y1s, nullptr, x1f, N1v, 1);
    grid.sync();
    // C2 = x1f@W2s_top, D2 = x1f@W2n_top
    dev_mm_f(x1f, w2t, w2nt, C2, D2, N1v, nt1v);
}

// bf16-A dual GEMM with next-tile A prefetch: bf16 O1 + fp8 O2 with ddst
// C2/D2 gather-add (layer-2 big).
__global__ __launch_bounds__(256, 2) void dualmm_regb_kernel(
    const ushort* __restrict__ Ab,
    const ushort* __restrict__ w1, const ushort* __restrict__ w2,
    const int* __restrict__ ddst,
    const float* __restrict__ C2g, const float* __restrict__ D2g,
    ushort* __restrict__ O1b, unsigned char* __restrict__ O2f8,
    int N, int ntiles) {
    const int tid = threadIdx.x;
    const int wave = tid >> 6, lane = tid & 63;
    const int m = lane & 15, quad = lane >> 4;
    const int colbase = wave * 32;
    bf16x8 bf[4][2][2];
    #pragma unroll
    for (int c = 0; c < 4; ++c)
        #pragma unroll
        for (int ct = 0; ct < 2; ++ct) {
            const size_t bo = (size_t)(colbase + ct * 16 + m) * 128 + c * 32 + quad * 8;
            bf[c][ct][0] = *(const bf16x8*)(w1 + bo);
            bf[c][ct][1] = *(const bf16x8*)(w2 + bo);
        }
    const f32x4 zero = {0.f, 0.f, 0.f, 0.f};
    bf16x8 pab[4];
    auto ldA = [&](int tile) {
        const int r0 = tile * 16;
        int ar = r0 + m; if (ar >= N) ar = N - 1;
        const ushort* arow = Ab + (size_t)ar * 128;
        #pragma unroll
        for (int c = 0; c < 4; ++c)
            pab[c] = *(const bf16x8*)(arow + c * 32 + quad * 8);
    };
    if ((int)blockIdx.x < ntiles) ldA(blockIdx.x);
    for (int tile = blockIdx.x; tile < ntiles; tile += gridDim.x) {
        bf16x8 ca[4];
        #pragma unroll
        for (int c = 0; c < 4; ++c) ca[c] = pab[c];
        const int nxt = tile + gridDim.x;
        if (nxt < ntiles) ldA(nxt);          // issue next-tile loads early
        f32x4 acc[2][2];
        acc[0][0] = zero; acc[0][1] = zero; acc[1][0] = zero; acc[1][1] = zero;
        #pragma unroll
        for (int c = 0; c < 4; ++c) {
            #pragma unroll
            for (int ct = 0; ct < 2; ++ct) {
                acc[ct][0] = __builtin_amdgcn_mfma_f32_16x16x32_bf16(bf[c][ct][0], ca[c], acc[ct][0], 0, 0, 0);
                acc[ct][1] = __builtin_amdgcn_mfma_f32_16x16x32_bf16(bf[c][ct][1], ca[c], acc[ct][1], 0, 0, 0);
            }
        }
        const int r = tile * 16 + m;
        const bool live = (r < N);
        int cc = live ? ddst[r] : 0;
        #pragma unroll
        for (int ct = 0; ct < 2; ++ct) {
            const int wc = colbase + ct * 16 + quad * 4;
            float4 g1 = make_float4(0.f, 0.f, 0.f, 0.f), g2 = g1;
            if (live) {
                g1 = *(const float4*)&C2g[(size_t)cc * D_DIM + wc];
                g2 = *(const float4*)&D2g[(size_t)cc * D_DIM + wc];
            }
            float o1[4], o2[4];
            o1[0] = acc[ct][0][0] + g1.x; o1[1] = acc[ct][0][1] + g1.y;
            o1[2] = acc[ct][0][2] + g1.z; o1[3] = acc[ct][0][3] + g1.w;
            o2[0] = acc[ct][1][0] + g2.x; o2[1] = acc[ct][1][1] + g2.y;
            o2[2] = acc[ct][1][2] + g2.z; o2[3] = acc[ct][1][3] + g2.w;
            if (live) {
                uint2 u;
                u.x = (uint)f2bf_rne(o1[0]) | ((uint)f2bf_rne(o1[1]) << 16);
                u.y = (uint)f2bf_rne(o1[2]) | ((uint)f2bf_rne(o1[3]) << 16);
                *(uint2*)&O1b[(size_t)r * D_DIM + wc] = u;
                int pk = __builtin_amdgcn_cvt_pk_fp8_f32(o2[0], o2[1], 0, false);
                pk = __builtin_amdgcn_cvt_pk_fp8_f32(o2[2], o2[3], pk, true);
                *(uint*)&O2f8[(size_t)r * D_DIM + wc] = (uint)pk;
            }
        }
    }
}

// ---------------------------------------------------------------------------
// softmax final: merge B per-block partials (written by readout gather),
// then write normalized output.
// ---------------------------------------------------------------------------
__global__ __launch_bounds__(256) void softmax_final_kernel(
    const float* __restrict__ z, const float* __restrict__ red,
    float* __restrict__ out, int N, int B) {
    __shared__ float sm[4], ss[4];
    __shared__ float sm_s, ss_s;
    int t = threadIdx.x, lane = t & 63, w = t >> 6;
    float m = -1e30f, s = 0.f;
    for (int i = t; i < B; i += 256) online2(m, s, red[2 * i], red[2 * i + 1]);
    #pragma unroll
    for (int off = 32; off > 0; off >>= 1) {
        float mo = __shfl_down(m, off), so = __shfl_down(s, off);
        online2(m, s, mo, so);
    }
    if (lane == 0) { sm[w] = m; ss[w] = s; }
    __syncthreads();
    if (t == 0) {
        for (int i = 1; i < 4; ++i) online2(m, s, sm[i], ss[i]);
        sm_s = m; ss_s = s;
    }
    __syncthreads();
    float mx = sm_s, sum = ss_s;
    for (int i = blockIdx.x * 256 + t; i < N; i += gridDim.x * 256)
        out[i] = expf(z[i] - mx) / sum;
}

// ---------------------------------------------------------------------------
// Host launcher
// ---------------------------------------------------------------------------
static inline char* align_up(char* p, size_t a) {
    return (char*)(((uintptr_t)p + a - 1) & ~(uintptr_t)(a - 1));
}

extern "C" void kernel_launch(void* const* d_in, const int* in_sizes, int n_in,
                              void* d_out, int out_size, void* d_ws, size_t ws_size,
                              hipStream_t stream) {
    const int N0 = N0_C, N1 = N1_C, E0 = E0_C, E1 = E1_C;
    const float* X   = (const float*)d_in[0];
    const float* W0s = (const float*)d_in[1];
    const float* W0n = (const float*)d_in[2];
    const float* b0  = (const float*)d_in[3];
    const float* W1s = (const float*)d_in[4];
    const float* W1n = (const float*)d_in[5];
    const float* b1  = (const float*)d_in[6];
    const float* W2s = (const float*)d_in[7];
    const float* W2n = (const float*)d_in[8];
    const float* b2  = (const float*)d_in[9];
    const float* Wm  = (const float*)d_in[10];
    const float* bm  = (const float*)d_in[11];
    const int* src0  = (const int*)d_in[12];
    const int* dst0  = (const int*)d_in[13];
    const int* src1  = (const int*)d_in[14];
    const int* dst1  = (const int*)d_in[15];
    const int* dsrc  = (const int*)d_in[16];
    const int* ddst  = (const int*)d_in[17];
    float* out = (float*)d_out;

    char* p = (char*)d_ws;
    const size_t FB = (size_t)N0 * D_DIM;
    const size_t SB = (size_t)N1 * D_DIM;
    auto grab_f = [&](size_t nf) { p = align_up(p, 256); float* r = (float*)p; p += nf * 4; return r; };
    auto grab_i = [&](size_t ni) { p = align_up(p, 256); int* r = (int*)p; p += ni * 4; return r; };
    auto grab_u = [&](size_t nu) { p = align_up(p, 256); ushort* r = (ushort*)p; p += nu * 2; return r; };
    auto grab_b = [&](size_t nb) { p = align_up(p, 256); unsigned char* r = (unsigned char*)p; p += nb; return r; };

    // zero-init region (zeroed by wtprep block 512): [bincur0 512 | bincur1 256 | bincurD 256]
    int* zeroRegion = grab_i(1024);
    int* bincur0 = zeroRegion;
    int* bincur1 = zeroRegion + 512;
    int* bincurD = zeroRegion + 768;

    float* y1s  = grab_f(SB);
    float* x1f  = grab_f(SB);
    float* C2   = grab_f(SB);
    float* D2   = grab_f(SB);
    float* zbuf = grab_f(N0);
    float* red  = grab_f(2 * ((N0 + 7) / 8) + 32);
    ushort* y0sb = grab_u(FB);
    ushort* x0b  = grab_u(FB);
    ushort* y2sb = grab_u(FB);
    ushort* x1bb = grab_u(SB);
    ushort* y1nb = grab_u(SB);
    unsigned char* y0nf8 = grab_b(FB);
    unsigned char* y2nf8 = grab_b(FB);
    ushort* wt   = grab_u(8 * 16384);
    int* pairs0 = grab_i((size_t)NB0_C * CAP0);
    int* pairs1 = grab_i((size_t)NB1_C * CAP1);
    int* pairsD = grab_i((size_t)NB1_C * CAPD);
    int* col0 = grab_i((size_t)NB0_C * CAP0);
    int* col1 = grab_i((size_t)NB1_C * CAP1);
    int* colD = grab_i((size_t)NB1_C * CAPD);
    int* beg0 = grab_i(N0); int* end0 = grab_i(N0);
    int* beg1 = grab_i(N1); int* end1 = grab_i(N1);
    int* begD = grab_i(N1); int* endD = grab_i(N1);
    (void)ws_size; (void)n_in; (void)in_sizes; (void)out_size;

    const int BT = 256;
    auto cdiv = [](int a, int b) { return (a + b - 1) / b; };
    auto WT = [&](int mi) { return wt + ((size_t)mi << 14); };
    const int nt0 = cdiv(N0, 16);
    const int nt1 = cdiv(N1, 16);
    const int nb0 = cdiv(E0, 4096);        // 196
    const int nb1 = cdiv(E1, 4096);        // 20
    const int nbd = cdiv(N0, 4096);        // 13
    const int G0 = 512;
    const int NBRO = cdiv(N0, 8);          // 6250 readout blocks (exact: 50000/8)

    // weights -> bf16 col-major  (+ block 512 zeros the counters)
    wtprep_kernel<<<513, BT, 0, stream>>>(W0s, W0n, W1s, W1n, W2s, W2n, wt, zeroRegion);

    // binned pair scatter (all 3 edge sets) + layer-0 dual GEMM, fused
    scatgemm_kernel<<<nb0 + nb1 + nbd + G0, BT, 0, stream>>>(
        src0, dst0, src1, dst1, dsrc, ddst,
        bincur0, bincur1, bincurD, pairs0, pairs1, pairsD,
        nb0, nb1, nbd,
        X, WT(0), WT(1), b0, y0sb, y0nf8, N0, nt0);

    // sort all bins -> global sorted colv + per-dst beg/end
    sortbins_kernel<<<NB0_C + 2 * NB1_C, BT, 0, stream>>>(
        pairs0, bincur0, pairs1, bincur1, pairsD, bincurD,
        col0, beg0, end0, col1, beg1, end1, colD, begD, endD);

    // x0 = y0s + mean_nbr(y0n)   (wide gather)
    csr_agg_big<1><<<NBRO, BT, 0, stream>>>(y0nf8, beg0, end0, col0,
        y0sb, nullptr, nullptr, x0b, nullptr, nullptr, nullptr, nullptr,
        nullptr, N0, 0);

    // cooperative N1 chain: down-pool -> mm1 -> graph1 agg -> mm2small
    {
        const ushort* w1sp = WT(2); const ushort* w1np = WT(3);
        const ushort* w2tp = WT(4); const ushort* w2ntp = WT(6);
        const ushort* x0bp = x0b; ushort* x1bbp = x1bb;
        const int* begDp = begD; const int* endDp = endD; const int* colDp = colD;
        const float* b1p = b1; float* y1sp = y1s; ushort* y1nbp = y1nb;
        const int* beg1p = beg1; const int* end1p = end1; const int* col1p = col1;
        float* x1fp = x1f; float* C2p = C2; float* D2p = D2;
        int n1v = N1, nt1v = nt1;
        void* cargs[] = {
            (void*)&x0bp, (void*)&begDp, (void*)&endDp, (void*)&colDp, (void*)&x1bbp,
            (void*)&w1sp, (void*)&w1np, (void*)&b1p, (void*)&y1sp, (void*)&y1nbp,
            (void*)&beg1p, (void*)&end1p, (void*)&col1p, (void*)&x1fp,
            (void*)&w2tp, (void*)&w2ntp, (void*)&C2p, (void*)&D2p,
            (void*)&n1v, (void*)&nt1v};
        hipLaunchCooperativeKernel((void*)coop_n1_kernel, dim3(256), dim3(BT),
                                   cargs, 0, stream);
    }

    // layer 2 big: y2s = x0@W2s_bot + C2[ddst], y2n = x0@W2n_bot + D2[ddst]
    dualmm_regb_kernel<<<G0, BT, 0, stream>>>(x0b, WT(5), WT(7),
        ddst, C2, D2, y2sb, y2nf8, N0, nt0);

    // layer 2 combine + readout z + per-block softmax partials
    csr_agg_big<1><<<NBRO, BT, 0, stream>>>(y2nf8, beg0, end0, col0,
        y2sb, nullptr, b2, nullptr, nullptr, Wm, bm, zbuf, red, N0, 1);

    // softmax final: merge 6250 partials, write out
    softmax_final_kernel<<<128, BT, 0, stream>>>(zbuf, red, out, N0, NBRO);
}

// Round 11
// 253.221 us; speedup vs baseline: 1.4924x; 1.4924x over previous
//
#include <hip/hip_runtime.h>
#include <hip/hip_bf16.h>
#include <cstdint>

#define D_DIM 128
#define N0_C 50000
#define N1_C 5000
#define E0_C 800000
#define E1_C 80000
#define NB0_C 391      // graph0 bins: 128 dsts each (shift 7)
#define CAP0 2560      // 2048 +/- 45 per bin, 11 sigma headroom
#define NB1_C 157      // N1-space bins: 32 dsts each (shift 5)
#define CAP1 640       // graph1: ~510/bin, +5.8 sigma
#define CAPD 512       // down:   ~318/bin, +10.9 sigma

typedef __attribute__((ext_vector_type(8))) short bf16x8;
typedef __attribute__((ext_vector_type(4))) float f32x4;
typedef __attribute__((ext_vector_type(2))) float f32x2;

__device__ __forceinline__ ushort f2bf_rne(float x) {
    unsigned int u = __float_as_uint(x);
    return (ushort)((u + 0x7FFFu + ((u >> 16) & 1u)) >> 16);
}
__device__ __forceinline__ float bf2f(ushort h) {
    return __uint_as_float(((unsigned int)h) << 16);
}
__device__ __forceinline__ int imin(int a, int b) { return a < b ? a : b; }
__device__ __forceinline__ void online2(float& m, float& s, float mo, float so) {
    if (mo > m) { s = s * __expf(m - mo) + so; m = mo; }
    else s += so * __expf(mo - m);
}
__device__ __forceinline__ void acc8_add_bf(float* acc, uint4 r) {
    acc[0] += __uint_as_float(r.x << 16);
    acc[1] += __uint_as_float(r.x & 0xFFFF0000u);
    acc[2] += __uint_as_float(r.y << 16);
    acc[3] += __uint_as_float(r.y & 0xFFFF0000u);
    acc[4] += __uint_as_float(r.z << 16);
    acc[5] += __uint_as_float(r.z & 0xFFFF0000u);
    acc[6] += __uint_as_float(r.w << 16);
    acc[7] += __uint_as_float(r.w & 0xFFFF0000u);
}
__device__ __forceinline__ void acc8_add_f8(float* acc, uint2 r) {
    f32x2 a = __builtin_amdgcn_cvt_pk_f32_fp8((int)r.x, false);
    f32x2 b = __builtin_amdgcn_cvt_pk_f32_fp8((int)r.x, true);
    f32x2 c = __builtin_amdgcn_cvt_pk_f32_fp8((int)r.y, false);
    f32x2 d = __builtin_amdgcn_cvt_pk_f32_fp8((int)r.y, true);
    acc[0] += a[0]; acc[1] += a[1]; acc[2] += b[0]; acc[3] += b[1];
    acc[4] += c[0]; acc[5] += c[1]; acc[6] += d[0]; acc[7] += d[1];
}

// ---------------------------------------------------------------------------
// weight prep + counter zeroing (memset launch folded in as block 512).
// wt mats 0:W0s 1:W0n 2:W1s 3:W1n 4:W2s_top 5:W2s_bot 6:W2n_top 7:W2n_bot,
// stored col-major bf16 (n*128 + k).
// ---------------------------------------------------------------------------
__global__ __launch_bounds__(256) void wtprep_kernel(
    const float* __restrict__ W0s, const float* __restrict__ W0n,
    const float* __restrict__ W1s, const float* __restrict__ W1n,
    const float* __restrict__ W2s, const float* __restrict__ W2n,
    ushort* __restrict__ wt, int* __restrict__ zr) {
    if (blockIdx.x >= 512) {
        #pragma unroll
        for (int i = 0; i < 4; ++i) zr[threadIdx.x + i * 256] = 0;
        return;
    }
    int gi = blockIdx.x * 256 + threadIdx.x;
    int mi = gi >> 14, idx = gi & 16383;
    int k = idx >> 7, n = idx & 127;
    const float* src; int row = k;
    switch (mi) {
        case 0: src = W0s; break;
        case 1: src = W0n; break;
        case 2: src = W1s; break;
        case 3: src = W1n; break;
        case 4: src = W2s; break;
        case 5: src = W2s; row = k + 128; break;
        case 6: src = W2n; break;
        default: src = W2n; row = k + 128; break;
    }
    wt[(mi << 14) + n * 128 + k] = f2bf_rne(src[row * 128 + n]);
}

// ---------------------------------------------------------------------------
// scatgemm: binned pair-scatter for all three edge sets (4096 edges/block)
// + layer-0 dual GEMM with next-tile A-prefetch.
// pair key = (local_dst << 17) | src   (src < 2^17, local < 128)
// ---------------------------------------------------------------------------
__global__ __launch_bounds__(256, 2) void scatgemm_kernel(
    const int* __restrict__ src0, const int* __restrict__ dst0,
    const int* __restrict__ src1, const int* __restrict__ dst1,
    const int* __restrict__ dsrc, const int* __restrict__ ddst,
    int* __restrict__ bincur0, int* __restrict__ bincur1, int* __restrict__ bincurD,
    int* __restrict__ pairs0, int* __restrict__ pairs1, int* __restrict__ pairsD,
    int nb0, int nb1, int nbd,
    const float* __restrict__ A,
    const ushort* __restrict__ w1, const ushort* __restrict__ w2,
    const float* __restrict__ bias1,
    ushort* __restrict__ O1b, unsigned char* __restrict__ O2f8,
    int N, int ntiles) {
    __shared__ int lcnt[512];
    __shared__ int sbase[512];
    const int b = blockIdx.x, t = threadIdx.x;
    const int nscat = nb0 + nb1 + nbd;
    if (b < nscat) {
        const int* srcp; const int* dstp; int* bc; int* pr;
        int e0, emax, shift, cap, nbins;
        if (b < nb0) {
            srcp = src0; dstp = dst0; bc = bincur0; pr = pairs0;
            e0 = b * 4096; emax = E0_C; shift = 7; cap = CAP0; nbins = NB0_C;
        } else if (b < nb0 + nb1) {
            srcp = src1; dstp = dst1; bc = bincur1; pr = pairs1;
            e0 = (b - nb0) * 4096; emax = E1_C; shift = 5; cap = CAP1; nbins = NB1_C;
        } else {
            srcp = dsrc; dstp = ddst; bc = bincurD; pr = pairsD;
            e0 = (b - nb0 - nb1) * 4096; emax = N0_C; shift = 5; cap = CAPD; nbins = NB1_C;
        }
        const int mask = (1 << shift) - 1;
        for (int i = t; i < 512; i += 256) lcnt[i] = 0;
        __syncthreads();
        int lrank[16], dloc[16];
        #pragma unroll
        for (int i = 0; i < 16; ++i) {
            int e = e0 + t + i * 256;
            if (e < emax) {
                int d = dstp[e];
                dloc[i] = d;
                lrank[i] = atomicAdd(&lcnt[d >> shift], 1);
            } else dloc[i] = -1;
        }
        __syncthreads();
        for (int i = t; i < nbins; i += 256)
            if (lcnt[i] > 0) sbase[i] = atomicAdd(&bc[i], lcnt[i]);
        __syncthreads();
        #pragma unroll
        for (int i = 0; i < 16; ++i) {
            int e = e0 + t + i * 256;
            if (e < emax) {
                int d = dloc[i];
                int bin = d >> shift;
                int key = ((d & mask) << 17) | srcp[e];
                pr[(size_t)bin * cap + sbase[bin] + lrank[i]] = key;
            }
        }
        return;
    }
    // ---- layer-0 dual GEMM (swapped operands; next-tile A prefetch) ----
    const int gstride = gridDim.x - nscat;
    const int bid = b - nscat;
    const int wave = t >> 6, lane = t & 63;
    const int m = lane & 15, quad = lane >> 4;
    const int colbase = wave * 32;
    bf16x8 bf[4][2][2];
    #pragma unroll
    for (int c = 0; c < 4; ++c)
        #pragma unroll
        for (int ct = 0; ct < 2; ++ct) {
            const size_t bo = (size_t)(colbase + ct * 16 + m) * 128 + c * 32 + quad * 8;
            bf[c][ct][0] = *(const bf16x8*)(w1 + bo);
            bf[c][ct][1] = *(const bf16x8*)(w2 + bo);
        }
    const f32x4 zero = {0.f, 0.f, 0.f, 0.f};
    float4 pa0[4], pa1[4];
    auto ldA = [&](int tile) {
        const int r0 = tile * 16;
        int ar = r0 + m; if (ar >= N) ar = N - 1;
        const float* arow = A + (size_t)ar * 128;
        #pragma unroll
        for (int c = 0; c < 4; ++c) {
            pa0[c] = *(const float4*)(arow + c * 32 + quad * 8);
            pa1[c] = *(const float4*)(arow + c * 32 + quad * 8 + 4);
        }
    };
    if (bid < ntiles) ldA(bid);
    for (int tile = bid; tile < ntiles; tile += gstride) {
        float4 ca0[4], ca1[4];
        #pragma unroll
        for (int c = 0; c < 4; ++c) { ca0[c] = pa0[c]; ca1[c] = pa1[c]; }
        const int nxt = tile + gstride;
        if (nxt < ntiles) ldA(nxt);          // issue next-tile loads early
        f32x4 acc[2][2];
        acc[0][0] = zero; acc[0][1] = zero; acc[1][0] = zero; acc[1][1] = zero;
        #pragma unroll
        for (int c = 0; c < 4; ++c) {
            float av[8] = {ca0[c].x, ca0[c].y, ca0[c].z, ca0[c].w,
                           ca1[c].x, ca1[c].y, ca1[c].z, ca1[c].w};
            bf16x8 afh, afl;
            #pragma unroll
            for (int i = 0; i < 8; ++i) {
                ushort h = f2bf_rne(av[i]);
                ushort l = f2bf_rne(av[i] - bf2f(h));
                afh[i] = (short)h; afl[i] = (short)l;
            }
            #pragma unroll
            for (int ct = 0; ct < 2; ++ct) {
                acc[ct][0] = __builtin_amdgcn_mfma_f32_16x16x32_bf16(bf[c][ct][0], afh, acc[ct][0], 0, 0, 0);
                acc[ct][0] = __builtin_amdgcn_mfma_f32_16x16x32_bf16(bf[c][ct][0], afl, acc[ct][0], 0, 0, 0);
                acc[ct][1] = __builtin_amdgcn_mfma_f32_16x16x32_bf16(bf[c][ct][1], afh, acc[ct][1], 0, 0, 0);
                acc[ct][1] = __builtin_amdgcn_mfma_f32_16x16x32_bf16(bf[c][ct][1], afl, acc[ct][1], 0, 0, 0);
            }
        }
        const int r = tile * 16 + m;
        #pragma unroll
        for (int ct = 0; ct < 2; ++ct) {
            const int wc = colbase + ct * 16 + quad * 4;
            float4 bv = bias1 ? *(const float4*)&bias1[wc] : make_float4(0.f, 0.f, 0.f, 0.f);
            float o1[4], o2[4];
            o1[0] = acc[ct][0][0] + bv.x; o1[1] = acc[ct][0][1] + bv.y;
            o1[2] = acc[ct][0][2] + bv.z; o1[3] = acc[ct][0][3] + bv.w;
            o2[0] = acc[ct][1][0]; o2[1] = acc[ct][1][1];
            o2[2] = acc[ct][1][2]; o2[3] = acc[ct][1][3];
            if (r < N) {
                uint2 u;
                u.x = (uint)f2bf_rne(o1[0]) | ((uint)f2bf_rne(o1[1]) << 16);
                u.y = (uint)f2bf_rne(o1[2]) | ((uint)f2bf_rne(o1[3]) << 16);
                *(uint2*)&O1b[(size_t)r * D_DIM + wc] = u;
                int pk = __builtin_amdgcn_cvt_pk_fp8_f32(o2[0], o2[1], 0, false);
                pk = __builtin_amdgcn_cvt_pk_fp8_f32(o2[2], o2[3], pk, true);
                *(uint*)&O2f8[(size_t)r * D_DIM + wc] = (uint)pk;
            }
        }
    }
}

// ---------------------------------------------------------------------------
// sortbins: one block per bin (all three edge sets). In-LDS rank + scan ->
// sorted colv written back to GLOBAL (coalesced) + per-dst beg/end arrays.
// ---------------------------------------------------------------------------
__global__ __launch_bounds__(256) void sortbins_kernel(
    const int* __restrict__ pairs0, const int* __restrict__ bincur0,
    const int* __restrict__ pairs1, const int* __restrict__ bincur1,
    const int* __restrict__ pairsD, const int* __restrict__ bincurD,
    int* __restrict__ col0, int* __restrict__ beg0, int* __restrict__ end0,
    int* __restrict__ col1, int* __restrict__ beg1, int* __restrict__ end1,
    int* __restrict__ colD, int* __restrict__ begD, int* __restrict__ endD) {
    __shared__ int cols[CAP0];
    __shared__ int cur[128];
    __shared__ int wtot_s;
    const int tid = threadIdx.x;
    int b = blockIdx.x;
    const int* pr; const int* bc; int* cg; int* bg; int* eg;
    int cap, nloc, nbase, nmax;
    if (b < NB0_C) {
        pr = pairs0; bc = bincur0; cg = col0; bg = beg0; eg = end0;
        cap = CAP0; nloc = 128; nbase = b << 7; nmax = N0_C;
    } else if (b < NB0_C + NB1_C) {
        b -= NB0_C;
        pr = pairs1; bc = bincur1; cg = col1; bg = beg1; eg = end1;
        cap = CAP1; nloc = 32; nbase = b << 5; nmax = N1_C;
    } else {
        b -= NB0_C + NB1_C;
        pr = pairsD; bc = bincurD; cg = colD; bg = begD; eg = endD;
        cap = CAPD; nloc = 32; nbase = b << 5; nmax = N1_C;
    }
    const size_t base = (size_t)b * cap;
    int cnt = bc[b]; if (cnt > cap) cnt = cap;
    if (tid < 128) cur[tid] = 0;
    __syncthreads();
    int key[10], rank[10];
    #pragma unroll
    for (int k = 0; k < 10; ++k) {
        int idx = tid + k * 256;
        key[k] = (idx < cnt) ? pr[base + idx] : -1;
    }
    #pragma unroll
    for (int k = 0; k < 10; ++k)
        if (key[k] >= 0) rank[k] = atomicAdd(&cur[key[k] >> 17], 1);
    __syncthreads();
    __shared__ int rp[129];
    int v = 0, x = 0;
    if (tid < 128) {
        v = cur[tid];
        x = v;
        int lane = tid & 63;
        #pragma unroll
        for (int off = 1; off < 64; off <<= 1) {
            int y = __shfl_up(x, off);
            if (lane >= off) x += y;
        }
        if (tid == 63) wtot_s = x;
    }
    __syncthreads();
    if (tid < 128) {
        int excl = x - v + ((tid >= 64) ? wtot_s : 0);
        rp[tid] = excl;
        if (tid == 127) rp[128] = excl + v;
        if (tid < nloc) {
            int n = nbase + tid;
            if (n < nmax) {
                bg[n] = (int)base + excl;
                eg[n] = (int)base + excl + v;
            }
        }
    }
    __syncthreads();
    #pragma unroll
    for (int k = 0; k < 10; ++k)
        if (key[k] >= 0)
            cols[rp[key[k] >> 17] + rank[k]] = key[k] & 0x1FFFF;
    __syncthreads();
    for (int i = tid; i < cnt; i += 256) cg[base + i] = cols[i];
}

// ---------------------------------------------------------------------------
// big CSR gather-aggregate, 2 nodes/wave; FP8 (128B rows) or bf16 (256B rows).
// Optional bf16 addvb OR f32 addvf; out bf16 outb OR f32 outf OR fused
// readout z = (...)@Wm + bm with per-block online-softmax partial to redp
// (requires exact grid: every block fully populated).
// ---------------------------------------------------------------------------
template <int FP8>
__global__ __launch_bounds__(256) void csr_agg_big(
    const void* __restrict__ featv,
    const int* __restrict__ rpbeg, const int* __restrict__ rpend,
    const int* __restrict__ colv,
    const ushort* __restrict__ addvb, const float* __restrict__ addvf,
    const float* __restrict__ bias,
    ushort* __restrict__ outb, float* __restrict__ outf,
    const float* __restrict__ Wm, const float* __restrict__ bm,
    float* __restrict__ z, float* __restrict__ redp, int Ndst, int do_relu) {
    __shared__ float zsh[8];
    const char* feat = (const char*)featv;
    int gt = blockIdx.x * blockDim.x + threadIdx.x;
    int wp = gt >> 6;
    int nA = wp * 2;
    if (nA >= Ndst) return;
    int nB = nA + 1;
    bool hasB = (nB < Ndst);
    int lane = threadIdx.x & 63;
    int q = lane >> 4, li = lane & 15;
    float accA[8], accB[8];
    #pragma unroll
    for (int i = 0; i < 8; ++i) { accA[i] = 0.f; accB[i] = 0.f; }
    int begA = rpbeg[nA], endA = rpend[nA];
    int begB = 0, endB = 0;
    if (hasB) { begB = rpbeg[nB]; endB = rpend[nB]; }
    int degA = endA - begA, degB = endB - begB;
    int lastA = (degA > 0) ? endA - 1 : 0;
    int lastB = (degB > 0) ? endB - 1 : 0;
    int jA = begA + q, jB = begB + q;
    while (jA < endA || jB < endB) {
        int ia[4], ib[4];
        #pragma unroll
        for (int k = 0; k < 4; ++k) {
            ia[k] = imin(jA + 4 * k, lastA);
            ib[k] = imin(jB + 4 * k, lastB);
        }
        if (FP8) {
            uint2 va[4], vb[4];
            #pragma unroll
            for (int k = 0; k < 4; ++k) {
                int ra = colv[ia[k]];
                va[k] = *(const uint2*)(feat + (size_t)ra * 128 + li * 8);
            }
            #pragma unroll
            for (int k = 0; k < 4; ++k) {
                int rb = colv[ib[k]];
                vb[k] = *(const uint2*)(feat + (size_t)rb * 128 + li * 8);
            }
            #pragma unroll
            for (int k = 0; k < 4; ++k) {
                if (jA + 4 * k < endA) acc8_add_f8(accA, va[k]);
                if (jB + 4 * k < endB) acc8_add_f8(accB, vb[k]);
            }
        } else {
            uint4 va[4], vb[4];
            #pragma unroll
            for (int k = 0; k < 4; ++k) {
                int ra = colv[ia[k]];
                va[k] = *(const uint4*)(feat + (size_t)ra * 256 + li * 16);
            }
            #pragma unroll
            for (int k = 0; k < 4; ++k) {
                int rb = colv[ib[k]];
                vb[k] = *(const uint4*)(feat + (size_t)rb * 256 + li * 16);
            }
            #pragma unroll
            for (int k = 0; k < 4; ++k) {
                if (jA + 4 * k < endA) acc8_add_bf(accA, va[k]);
                if (jB + 4 * k < endB) acc8_add_bf(accB, vb[k]);
            }
        }
        jA += 16; jB += 16;
    }
    const int f8 = li * 8;
    #pragma unroll
    for (int i = 0; i < 8; ++i) {
        accA[i] += __shfl_xor(accA[i], 16);
        accA[i] += __shfl_xor(accA[i], 32);
        accB[i] += __shfl_xor(accB[i], 16);
        accB[i] += __shfl_xor(accB[i], 32);
    }
    float invA = 1.f / fmaxf((float)degA, 1.f);
    float invB = 1.f / fmaxf((float)degB, 1.f);
    #pragma unroll
    for (int i = 0; i < 8; ++i) { accA[i] *= invA; accB[i] *= invB; }
    if (addvb) {
        uint4 a = *(const uint4*)&addvb[(size_t)nA * D_DIM + f8];
        acc8_add_bf(accA, a);
        if (hasB) {
            uint4 b = *(const uint4*)&addvb[(size_t)nB * D_DIM + f8];
            acc8_add_bf(accB, b);
        }
    }
    if (addvf) {
        float4 g0 = *(const float4*)&addvf[(size_t)nA * D_DIM + f8];
        float4 g1 = *(const float4*)&addvf[(size_t)nA * D_DIM + f8 + 4];
        accA[0] += g0.x; accA[1] += g0.y; accA[2] += g0.z; accA[3] += g0.w;
        accA[4] += g1.x; accA[5] += g1.y; accA[6] += g1.z; accA[7] += g1.w;
        if (hasB) {
            float4 h0 = *(const float4*)&addvf[(size_t)nB * D_DIM + f8];
            float4 h1 = *(const float4*)&addvf[(size_t)nB * D_DIM + f8 + 4];
            accB[0] += h0.x; accB[1] += h0.y; accB[2] += h0.z; accB[3] += h0.w;
            accB[4] += h1.x; accB[5] += h1.y; accB[6] += h1.z; accB[7] += h1.w;
        }
    }
    if (bias) {
        float4 b0 = *(const float4*)&bias[f8];
        float4 b1 = *(const float4*)&bias[f8 + 4];
        accA[0] += b0.x; accA[1] += b0.y; accA[2] += b0.z; accA[3] += b0.w;
        accA[4] += b1.x; accA[5] += b1.y; accA[6] += b1.z; accA[7] += b1.w;
        accB[0] += b0.x; accB[1] += b0.y; accB[2] += b0.z; accB[3] += b0.w;
        accB[4] += b1.x; accB[5] += b1.y; accB[6] += b1.z; accB[7] += b1.w;
    }
    if (do_relu) {
        #pragma unroll
        for (int i = 0; i < 8; ++i) {
            accA[i] = fmaxf(accA[i], 0.f);
            accB[i] = fmaxf(accB[i], 0.f);
        }
    }
    if (outb) {
        if (q == 0) {
            uint4 o;
            o.x = (uint)f2bf_rne(accA[0]) | ((uint)f2bf_rne(accA[1]) << 16);
            o.y = (uint)f2bf_rne(accA[2]) | ((uint)f2bf_rne(accA[3]) << 16);
            o.z = (uint)f2bf_rne(accA[4]) | ((uint)f2bf_rne(accA[5]) << 16);
            o.w = (uint)f2bf_rne(accA[6]) | ((uint)f2bf_rne(accA[7]) << 16);
            *(uint4*)&outb[(size_t)nA * D_DIM + f8] = o;
        } else if (q == 1 && hasB) {
            uint4 o;
            o.x = (uint)f2bf_rne(accB[0]) | ((uint)f2bf_rne(accB[1]) << 16);
            o.y = (uint)f2bf_rne(accB[2]) | ((uint)f2bf_rne(accB[3]) << 16);
            o.z = (uint)f2bf_rne(accB[4]) | ((uint)f2bf_rne(accB[5]) << 16);
            o.w = (uint)f2bf_rne(accB[6]) | ((uint)f2bf_rne(accB[7]) << 16);
            *(uint4*)&outb[(size_t)nB * D_DIM + f8] = o;
        }
    } else if (outf) {
        if (q == 0) {
            float4 s0, s1;
            s0.x = accA[0]; s0.y = accA[1]; s0.z = accA[2]; s0.w = accA[3];
            s1.x = accA[4]; s1.y = accA[5]; s1.z = accA[6]; s1.w = accA[7];
            *(float4*)&outf[(size_t)nA * D_DIM + f8] = s0;
            *(float4*)&outf[(size_t)nA * D_DIM + f8 + 4] = s1;
        } else if (q == 1 && hasB) {
            float4 s0, s1;
            s0.x = accB[0]; s0.y = accB[1]; s0.z = accB[2]; s0.w = accB[3];
            s1.x = accB[4]; s1.y = accB[5]; s1.z = accB[6]; s1.w = accB[7];
            *(float4*)&outf[(size_t)nB * D_DIM + f8] = s0;
            *(float4*)&outf[(size_t)nB * D_DIM + f8 + 4] = s1;
        }
    }
    if (z) {
        float4 w0 = *(const float4*)&Wm[f8];
        float4 w1 = *(const float4*)&Wm[f8 + 4];
        float p = 0.f;
        if (q == 0)
            p = accA[0] * w0.x + accA[1] * w0.y + accA[2] * w0.z + accA[3] * w0.w
              + accA[4] * w1.x + accA[5] * w1.y + accA[6] * w1.z + accA[7] * w1.w;
        else if (q == 1)
            p = accB[0] * w0.x + accB[1] * w0.y + accB[2] * w0.z + accB[3] * w0.w
              + accB[4] * w1.x + accB[5] * w1.y + accB[6] * w1.z + accB[7] * w1.w;
        #pragma unroll
        for (int off = 8; off > 0; off >>= 1) p += __shfl_down(p, off);
        const int wv = threadIdx.x >> 6;
        if (lane == 0) {
            float zv = p + bm[0];
            z[nA] = zv;
            if (redp) zsh[2 * wv] = zv;
        }
        if (lane == 16 && hasB) {
            float zv = p + bm[0];
            z[nB] = zv;
            if (redp) zsh[2 * wv + 1] = zv;
        }
        if (redp) {
            __syncthreads();
            if (threadIdx.x == 0) {
                float m = -1e30f, s = 0.f;
                #pragma unroll
                for (int i = 0; i < 8; ++i) {
                    float v = zsh[i];
                    if (v > m) { s = s * __expf(m - v) + 1.f; m = v; }
                    else s += __expf(v - m);
                }
                redp[2 * blockIdx.x] = m;
                redp[2 * blockIdx.x + 1] = s;
            }
        }
    }
}

// ---------------------------------------------------------------------------
// standalone dual GEMM, fp32 A (hi/lo split), fp32 outs (layer-2 small C2/D2)
// ---------------------------------------------------------------------------
__global__ __launch_bounds__(256, 2) void dualmm_reg_kernel(
    const float* __restrict__ A,
    const ushort* __restrict__ w1, const ushort* __restrict__ w2,
    const float* __restrict__ bias1,
    float* __restrict__ O1f, float* __restrict__ O2f, int N, int ntiles) {
    const int tid = threadIdx.x;
    const int wave = tid >> 6, lane = tid & 63;
    const int m = lane & 15, quad = lane >> 4;
    const int colbase = wave * 32;
    bf16x8 bf[4][2][2];
    #pragma unroll
    for (int c = 0; c < 4; ++c)
        #pragma unroll
        for (int ct = 0; ct < 2; ++ct) {
            const size_t bo = (size_t)(colbase + ct * 16 + m) * 128 + c * 32 + quad * 8;
            bf[c][ct][0] = *(const bf16x8*)(w1 + bo);
            bf[c][ct][1] = *(const bf16x8*)(w2 + bo);
        }
    const f32x4 zero = {0.f, 0.f, 0.f, 0.f};
    for (int tile = blockIdx.x; tile < ntiles; tile += gridDim.x) {
        const int r0 = tile * 16;
        int ar = r0 + m; if (ar >= N) ar = N - 1;
        const float* arow = A + (size_t)ar * 128;
        f32x4 acc[2][2];
        acc[0][0] = zero; acc[0][1] = zero; acc[1][0] = zero; acc[1][1] = zero;
        #pragma unroll
        for (int c = 0; c < 4; ++c) {
            float4 a0 = *(const float4*)(arow + c * 32 + quad * 8);
            float4 a1 = *(const float4*)(arow + c * 32 + quad * 8 + 4);
            float av[8] = {a0.x, a0.y, a0.z, a0.w, a1.x, a1.y, a1.z, a1.w};
            bf16x8 afh, afl;
            #pragma unroll
            for (int i = 0; i < 8; ++i) {
                ushort h = f2bf_rne(av[i]);
                ushort l = f2bf_rne(av[i] - bf2f(h));
                afh[i] = (short)h; afl[i] = (short)l;
            }
            #pragma unroll
            for (int ct = 0; ct < 2; ++ct) {
                acc[ct][0] = __builtin_amdgcn_mfma_f32_16x16x32_bf16(bf[c][ct][0], afh, acc[ct][0], 0, 0, 0);
                acc[ct][0] = __builtin_amdgcn_mfma_f32_16x16x32_bf16(bf[c][ct][0], afl, acc[ct][0], 0, 0, 0);
                acc[ct][1] = __builtin_amdgcn_mfma_f32_16x16x32_bf16(bf[c][ct][1], afh, acc[ct][1], 0, 0, 0);
                acc[ct][1] = __builtin_amdgcn_mfma_f32_16x16x32_bf16(bf[c][ct][1], afl, acc[ct][1], 0, 0, 0);
            }
        }
        const int r = r0 + m;
        if (r < N) {
            #pragma unroll
            for (int ct = 0; ct < 2; ++ct) {
                const int wc = colbase + ct * 16 + quad * 4;
                float4 bv = bias1 ? *(const float4*)&bias1[wc] : make_float4(0.f, 0.f, 0.f, 0.f);
                float4 s1, s2;
                s1.x = acc[ct][0][0] + bv.x; s1.y = acc[ct][0][1] + bv.y;
                s1.z = acc[ct][0][2] + bv.z; s1.w = acc[ct][0][3] + bv.w;
                s2.x = acc[ct][1][0]; s2.y = acc[ct][1][1];
                s2.z = acc[ct][1][2]; s2.w = acc[ct][1][3];
                *(float4*)&O1f[(size_t)r * D_DIM + wc] = s1;
                *(float4*)&O2f[(size_t)r * D_DIM + wc] = s2;
            }
        }
    }
}

// bf16-A dual GEMM with next-tile A prefetch. Modes by output pointers:
//   O1b  != null : bf16 O1 + fp8 O2 (+optional ddst C2/D2 gather-add)
//   O2bb != null : f32 O1 + bf16 O2
//   else         : f32 + f32
__global__ __launch_bounds__(256, 2) void dualmm_regb_kernel(
    const ushort* __restrict__ Ab,
    const ushort* __restrict__ w1, const ushort* __restrict__ w2,
    const float* __restrict__ bias1,
    const int* __restrict__ ddst,
    const float* __restrict__ C2g, const float* __restrict__ D2g,
    float* __restrict__ O1f, ushort* __restrict__ O1b,
    float* __restrict__ O2f, unsigned char* __restrict__ O2f8,
    ushort* __restrict__ O2bb,
    int N, int ntiles) {
    const int tid = threadIdx.x;
    const int wave = tid >> 6, lane = tid & 63;
    const int m = lane & 15, quad = lane >> 4;
    const int colbase = wave * 32;
    bf16x8 bf[4][2][2];
    #pragma unroll
    for (int c = 0; c < 4; ++c)
        #pragma unroll
        for (int ct = 0; ct < 2; ++ct) {
            const size_t bo = (size_t)(colbase + ct * 16 + m) * 128 + c * 32 + quad * 8;
            bf[c][ct][0] = *(const bf16x8*)(w1 + bo);
            bf[c][ct][1] = *(const bf16x8*)(w2 + bo);
        }
    const f32x4 zero = {0.f, 0.f, 0.f, 0.f};
    bf16x8 pab[4];
    auto ldA = [&](int tile) {
        const int r0 = tile * 16;
        int ar = r0 + m; if (ar >= N) ar = N - 1;
        const ushort* arow = Ab + (size_t)ar * 128;
        #pragma unroll
        for (int c = 0; c < 4; ++c)
            pab[c] = *(const bf16x8*)(arow + c * 32 + quad * 8);
    };
    if ((int)blockIdx.x < ntiles) ldA(blockIdx.x);
    for (int tile = blockIdx.x; tile < ntiles; tile += gridDim.x) {
        bf16x8 ca[4];
        #pragma unroll
        for (int c = 0; c < 4; ++c) ca[c] = pab[c];
        const int nxt = tile + gridDim.x;
        if (nxt < ntiles) ldA(nxt);          // issue next-tile loads early
        f32x4 acc[2][2];
        acc[0][0] = zero; acc[0][1] = zero; acc[1][0] = zero; acc[1][1] = zero;
        #pragma unroll
        for (int c = 0; c < 4; ++c) {
            #pragma unroll
            for (int ct = 0; ct < 2; ++ct) {
                acc[ct][0] = __builtin_amdgcn_mfma_f32_16x16x32_bf16(bf[c][ct][0], ca[c], acc[ct][0], 0, 0, 0);
                acc[ct][1] = __builtin_amdgcn_mfma_f32_16x16x32_bf16(bf[c][ct][1], ca[c], acc[ct][1], 0, 0, 0);
            }
        }
        const int r = tile * 16 + m;
        const bool live = (r < N);
        int cc = (ddst && live) ? ddst[r] : 0;
        #pragma unroll
        for (int ct = 0; ct < 2; ++ct) {
            const int wc = colbase + ct * 16 + quad * 4;
            float4 bv = bias1 ? *(const float4*)&bias1[wc] : make_float4(0.f, 0.f, 0.f, 0.f);
            float4 g1 = make_float4(0.f, 0.f, 0.f, 0.f), g2 = g1;
            if (ddst && live) {
                g1 = *(const float4*)&C2g[(size_t)cc * D_DIM + wc];
                g2 = *(const float4*)&D2g[(size_t)cc * D_DIM + wc];
            }
            float o1[4], o2[4];
            o1[0] = acc[ct][0][0] + bv.x + g1.x; o1[1] = acc[ct][0][1] + bv.y + g1.y;
            o1[2] = acc[ct][0][2] + bv.z + g1.z; o1[3] = acc[ct][0][3] + bv.w + g1.w;
            o2[0] = acc[ct][1][0] + g2.x; o2[1] = acc[ct][1][1] + g2.y;
            o2[2] = acc[ct][1][2] + g2.z; o2[3] = acc[ct][1][3] + g2.w;
            if (live) {
                if (O1b) {
                    uint2 u;
                    u.x = (uint)f2bf_rne(o1[0]) | ((uint)f2bf_rne(o1[1]) << 16);
                    u.y = (uint)f2bf_rne(o1[2]) | ((uint)f2bf_rne(o1[3]) << 16);
                    *(uint2*)&O1b[(size_t)r * D_DIM + wc] = u;
                    int pk = __builtin_amdgcn_cvt_pk_fp8_f32(o2[0], o2[1], 0, false);
                    pk = __builtin_amdgcn_cvt_pk_fp8_f32(o2[2], o2[3], pk, true);
                    *(uint*)&O2f8[(size_t)r * D_DIM + wc] = (uint)pk;
                } else if (O2bb) {
                    float4 s1;
                    s1.x = o1[0]; s1.y = o1[1]; s1.z = o1[2]; s1.w = o1[3];
                    *(float4*)&O1f[(size_t)r * D_DIM + wc] = s1;
                    uint2 u;
                    u.x = (uint)f2bf_rne(o2[0]) | ((uint)f2bf_rne(o2[1]) << 16);
                    u.y = (uint)f2bf_rne(o2[2]) | ((uint)f2bf_rne(o2[3]) << 16);
                    *(uint2*)&O2bb[(size_t)r * D_DIM + wc] = u;
                } else {
                    float4 s1, s2;
                    s1.x = o1[0]; s1.y = o1[1]; s1.z = o1[2]; s1.w = o1[3];
                    s2.x = o2[0]; s2.y = o2[1]; s2.z = o2[2]; s2.w = o2[3];
                    *(float4*)&O1f[(size_t)r * D_DIM + wc] = s1;
                    *(float4*)&O2f[(size_t)r * D_DIM + wc] = s2;
                }
            }
        }
    }
}

// ---------------------------------------------------------------------------
// softmax final: merge B per-block partials (written by readout gather),
// then write normalized output.
// ---------------------------------------------------------------------------
__global__ __launch_bounds__(256) void softmax_final_kernel(
    const float* __restrict__ z, const float* __restrict__ red,
    float* __restrict__ out, int N, int B) {
    __shared__ float sm[4], ss[4];
    __shared__ float sm_s, ss_s;
    int t = threadIdx.x, lane = t & 63, w = t >> 6;
    float m = -1e30f, s = 0.f;
    for (int i = t; i < B; i += 256) online2(m, s, red[2 * i], red[2 * i + 1]);
    #pragma unroll
    for (int off = 32; off > 0; off >>= 1) {
        float mo = __shfl_down(m, off), so = __shfl_down(s, off);
        online2(m, s, mo, so);
    }
    if (lane == 0) { sm[w] = m; ss[w] = s; }
    __syncthreads();
    if (t == 0) {
        for (int i = 1; i < 4; ++i) online2(m, s, sm[i], ss[i]);
        sm_s = m; ss_s = s;
    }
    __syncthreads();
    float mx = sm_s, sum = ss_s;
    for (int i = blockIdx.x * 256 + t; i < N; i += gridDim.x * 256)
        out[i] = expf(z[i] - mx) / sum;
}

// ---------------------------------------------------------------------------
// Host launcher
// ---------------------------------------------------------------------------
static inline char* align_up(char* p, size_t a) {
    return (char*)(((uintptr_t)p + a - 1) & ~(uintptr_t)(a - 1));
}

extern "C" void kernel_launch(void* const* d_in, const int* in_sizes, int n_in,
                              void* d_out, int out_size, void* d_ws, size_t ws_size,
                              hipStream_t stream) {
    const int N0 = N0_C, N1 = N1_C, E0 = E0_C, E1 = E1_C;
    const float* X   = (const float*)d_in[0];
    const float* W0s = (const float*)d_in[1];
    const float* W0n = (const float*)d_in[2];
    const float* b0  = (const float*)d_in[3];
    const float* W1s = (const float*)d_in[4];
    const float* W1n = (const float*)d_in[5];
    const float* b1  = (const float*)d_in[6];
    const float* W2s = (const float*)d_in[7];
    const float* W2n = (const float*)d_in[8];
    const float* b2  = (const float*)d_in[9];
    const float* Wm  = (const float*)d_in[10];
    const float* bm  = (const float*)d_in[11];
    const int* src0  = (const int*)d_in[12];
    const int* dst0  = (const int*)d_in[13];
    const int* src1  = (const int*)d_in[14];
    const int* dst1  = (const int*)d_in[15];
    const int* dsrc  = (const int*)d_in[16];
    const int* ddst  = (const int*)d_in[17];
    float* out = (float*)d_out;

    char* p = (char*)d_ws;
    const size_t FB = (size_t)N0 * D_DIM;
    const size_t SB = (size_t)N1 * D_DIM;
    auto grab_f = [&](size_t nf) { p = align_up(p, 256); float* r = (float*)p; p += nf * 4; return r; };
    auto grab_i = [&](size_t ni) { p = align_up(p, 256); int* r = (int*)p; p += ni * 4; return r; };
    auto grab_u = [&](size_t nu) { p = align_up(p, 256); ushort* r = (ushort*)p; p += nu * 2; return r; };
    auto grab_b = [&](size_t nb) { p = align_up(p, 256); unsigned char* r = (unsigned char*)p; p += nb; return r; };

    // zero-init region (zeroed by wtprep block 512): [bincur0 512 | bincur1 256 | bincurD 256]
    int* zeroRegion = grab_i(1024);
    int* bincur0 = zeroRegion;
    int* bincur1 = zeroRegion + 512;
    int* bincurD = zeroRegion + 768;

    float* y1s  = grab_f(SB);
    float* x1f  = grab_f(SB);
    float* C2   = grab_f(SB);
    float* D2   = grab_f(SB);
    float* zbuf = grab_f(N0);
    float* red  = grab_f(2 * ((N0 + 7) / 8) + 32);
    ushort* y0sb = grab_u(FB);
    ushort* x0b  = grab_u(FB);
    ushort* y2sb = grab_u(FB);
    ushort* x1bb = grab_u(SB);
    ushort* y1nb = grab_u(SB);
    unsigned char* y0nf8 = grab_b(FB);
    unsigned char* y2nf8 = grab_b(FB);
    ushort* wt   = grab_u(8 * 16384);
    int* pairs0 = grab_i((size_t)NB0_C * CAP0);
    int* pairs1 = grab_i((size_t)NB1_C * CAP1);
    int* pairsD = grab_i((size_t)NB1_C * CAPD);
    int* col0 = grab_i((size_t)NB0_C * CAP0);
    int* col1 = grab_i((size_t)NB1_C * CAP1);
    int* colD = grab_i((size_t)NB1_C * CAPD);
    int* beg0 = grab_i(N0); int* end0 = grab_i(N0);
    int* beg1 = grab_i(N1); int* end1 = grab_i(N1);
    int* begD = grab_i(N1); int* endD = grab_i(N1);
    (void)ws_size; (void)n_in; (void)in_sizes; (void)out_size;

    const int BT = 256;
    auto cdiv = [](int a, int b) { return (a + b - 1) / b; };
    auto WT = [&](int mi) { return wt + ((size_t)mi << 14); };
    const int nt0 = cdiv(N0, 16);
    const int nt1 = cdiv(N1, 16);
    const int nb0 = cdiv(E0, 4096);        // 196
    const int nb1 = cdiv(E1, 4096);        // 20
    const int nbd = cdiv(N0, 4096);        // 13
    const int G0 = 512;
    const int NBRO = cdiv(N0, 8);          // 6250 readout blocks (exact: 50000/8)

    // weights -> bf16 col-major  (+ block 512 zeros the counters)
    wtprep_kernel<<<513, BT, 0, stream>>>(W0s, W0n, W1s, W1n, W2s, W2n, wt, zeroRegion);

    // binned pair scatter (all 3 edge sets) + layer-0 dual GEMM, fused
    scatgemm_kernel<<<nb0 + nb1 + nbd + G0, BT, 0, stream>>>(
        src0, dst0, src1, dst1, dsrc, ddst,
        bincur0, bincur1, bincurD, pairs0, pairs1, pairsD,
        nb0, nb1, nbd,
        X, WT(0), WT(1), b0, y0sb, y0nf8, N0, nt0);

    // sort all bins -> global sorted colv + per-dst beg/end
    sortbins_kernel<<<NB0_C + 2 * NB1_C, BT, 0, stream>>>(
        pairs0, bincur0, pairs1, bincur1, pairsD, bincurD,
        col0, beg0, end0, col1, beg1, end1, colD, begD, endD);

    // x0 = y0s + mean_nbr(y0n)   (wide gather)
    csr_agg_big<1><<<NBRO, BT, 0, stream>>>(y0nf8, beg0, end0, col0,
        y0sb, nullptr, nullptr, x0b, nullptr, nullptr, nullptr, nullptr,
        nullptr, N0, 0);

    // x1 = relu(mean_cluster(x0))
    csr_agg_big<0><<<cdiv(N1, 8), BT, 0, stream>>>(x0b, begD, endD, colD,
        nullptr, nullptr, nullptr, x1bb, nullptr, nullptr, nullptr, nullptr,
        nullptr, N1, 1);

    // layer 1 GEMM: y1s f32 (+b1), y1n bf16
    dualmm_regb_kernel<<<nt1, BT, 0, stream>>>(x1bb, WT(2), WT(3), b1,
        nullptr, nullptr, nullptr, y1s, nullptr, nullptr, nullptr, y1nb, N1, nt1);

    // x1f = relu(y1s + mean_nbr(y1n))
    csr_agg_big<0><<<cdiv(N1, 8), BT, 0, stream>>>(y1nb, beg1, end1, col1,
        nullptr, y1s, nullptr, nullptr, x1f, nullptr, nullptr, nullptr,
        nullptr, N1, 1);

    // layer 2 small: C2 = x1f@W2s_top, D2 = x1f@W2n_top (f32)
    dualmm_reg_kernel<<<nt1, BT, 0, stream>>>(x1f, WT(4), WT(6), nullptr,
        C2, D2, N1, nt1);

    // layer 2 big: y2s = x0@W2s_bot + C2[ddst], y2n = x0@W2n_bot + D2[ddst]
    dualmm_regb_kernel<<<G0, BT, 0, stream>>>(x0b, WT(5), WT(7), nullptr,
        ddst, C2, D2, nullptr, y2sb, nullptr, y2nf8, nullptr, N0, nt0);

    // layer 2 combine + readout z + per-block softmax partials
    csr_agg_big<1><<<NBRO, BT, 0, stream>>>(y2nf8, beg0, end0, col0,
        y2sb, nullptr, b2, nullptr, nullptr, Wm, bm, zbuf, red, N0, 1);

    // softmax final: merge 6250 partials, write out
    softmax_final_kernel<<<128, BT, 0, stream>>>(zbuf, red, out, N0, NBRO);
}

// Round 12
// 244.794 us; speedup vs baseline: 1.5438x; 1.0344x over previous
//
#include <hip/hip_runtime.h>
#include <hip/hip_bf16.h>
#include <cstdint>

#define D_DIM 128
#define N0_C 50000
#define N1_C 5000
#define E0_C 800000
#define E1_C 80000
#define NB0_C 391      // graph0 bins: 128 dsts each (shift 7)
#define CAP0 2560      // 2048 +/- 45 per bin, 11 sigma headroom
#define NB1_C 157      // N1-space bins: 32 dsts each (shift 5)
#define CAP1 640       // graph1: ~510/bin, +5.8 sigma
#define CAPD 512       // down:   ~318/bin, +10.9 sigma

typedef __attribute__((ext_vector_type(8))) short bf16x8;
typedef __attribute__((ext_vector_type(4))) float f32x4;
typedef __attribute__((ext_vector_type(2))) float f32x2;

__device__ __forceinline__ ushort f2bf_rne(float x) {
    unsigned int u = __float_as_uint(x);
    return (ushort)((u + 0x7FFFu + ((u >> 16) & 1u)) >> 16);
}
__device__ __forceinline__ float bf2f(ushort h) {
    return __uint_as_float(((unsigned int)h) << 16);
}
__device__ __forceinline__ int imin(int a, int b) { return a < b ? a : b; }
__device__ __forceinline__ void online2(float& m, float& s, float mo, float so) {
    if (mo > m) { s = s * __expf(m - mo) + so; m = mo; }
    else s += so * __expf(mo - m);
}
__device__ __forceinline__ void acc8_add_bf(float* acc, uint4 r) {
    acc[0] += __uint_as_float(r.x << 16);
    acc[1] += __uint_as_float(r.x & 0xFFFF0000u);
    acc[2] += __uint_as_float(r.y << 16);
    acc[3] += __uint_as_float(r.y & 0xFFFF0000u);
    acc[4] += __uint_as_float(r.z << 16);
    acc[5] += __uint_as_float(r.z & 0xFFFF0000u);
    acc[6] += __uint_as_float(r.w << 16);
    acc[7] += __uint_as_float(r.w & 0xFFFF0000u);
}
__device__ __forceinline__ void acc8_add_f8(float* acc, uint2 r) {
    f32x2 a = __builtin_amdgcn_cvt_pk_f32_fp8((int)r.x, false);
    f32x2 b = __builtin_amdgcn_cvt_pk_f32_fp8((int)r.x, true);
    f32x2 c = __builtin_amdgcn_cvt_pk_f32_fp8((int)r.y, false);
    f32x2 d = __builtin_amdgcn_cvt_pk_f32_fp8((int)r.y, true);
    acc[0] += a[0]; acc[1] += a[1]; acc[2] += b[0]; acc[3] += b[1];
    acc[4] += c[0]; acc[5] += c[1]; acc[6] += d[0]; acc[7] += d[1];
}

// ---------------------------------------------------------------------------
// weight prep + counter zeroing (memset launch folded in as block 512).
// wt mats 0:W0s 1:W0n 2:W1s 3:W1n 4:W2s_top 5:W2s_bot 6:W2n_top 7:W2n_bot,
// stored col-major bf16 (n*128 + k).
// ---------------------------------------------------------------------------
__global__ __launch_bounds__(256) void wtprep_kernel(
    const float* __restrict__ W0s, const float* __restrict__ W0n,
    const float* __restrict__ W1s, const float* __restrict__ W1n,
    const float* __restrict__ W2s, const float* __restrict__ W2n,
    ushort* __restrict__ wt, int* __restrict__ zr) {
    if (blockIdx.x >= 512) {
        #pragma unroll
        for (int i = 0; i < 4; ++i) zr[threadIdx.x + i * 256] = 0;
        return;
    }
    int gi = blockIdx.x * 256 + threadIdx.x;
    int mi = gi >> 14, idx = gi & 16383;
    int k = idx >> 7, n = idx & 127;
    const float* src; int row = k;
    switch (mi) {
        case 0: src = W0s; break;
        case 1: src = W0n; break;
        case 2: src = W1s; break;
        case 3: src = W1n; break;
        case 4: src = W2s; break;
        case 5: src = W2s; row = k + 128; break;
        case 6: src = W2n; break;
        default: src = W2n; row = k + 128; break;
    }
    wt[(mi << 14) + n * 128 + k] = f2bf_rne(src[row * 128 + n]);
}

// ---------------------------------------------------------------------------
// scatgemm: binned pair-scatter for all three edge sets (4096 edges/block)
// + layer-0 dual GEMM with next-tile A-prefetch.
// pair key = (local_dst << 17) | src   (src < 2^17, local < 128)
// ---------------------------------------------------------------------------
__global__ __launch_bounds__(256, 2) void scatgemm_kernel(
    const int* __restrict__ src0, const int* __restrict__ dst0,
    const int* __restrict__ src1, const int* __restrict__ dst1,
    const int* __restrict__ dsrc, const int* __restrict__ ddst,
    int* __restrict__ bincur0, int* __restrict__ bincur1, int* __restrict__ bincurD,
    int* __restrict__ pairs0, int* __restrict__ pairs1, int* __restrict__ pairsD,
    int nb0, int nb1, int nbd,
    const float* __restrict__ A,
    const ushort* __restrict__ w1, const ushort* __restrict__ w2,
    const float* __restrict__ bias1,
    ushort* __restrict__ O1b, unsigned char* __restrict__ O2f8,
    int N, int ntiles) {
    __shared__ int lcnt[512];
    __shared__ int sbase[512];
    const int b = blockIdx.x, t = threadIdx.x;
    const int nscat = nb0 + nb1 + nbd;
    if (b < nscat) {
        const int* srcp; const int* dstp; int* bc; int* pr;
        int e0, emax, shift, cap, nbins;
        if (b < nb0) {
            srcp = src0; dstp = dst0; bc = bincur0; pr = pairs0;
            e0 = b * 4096; emax = E0_C; shift = 7; cap = CAP0; nbins = NB0_C;
        } else if (b < nb0 + nb1) {
            srcp = src1; dstp = dst1; bc = bincur1; pr = pairs1;
            e0 = (b - nb0) * 4096; emax = E1_C; shift = 5; cap = CAP1; nbins = NB1_C;
        } else {
            srcp = dsrc; dstp = ddst; bc = bincurD; pr = pairsD;
            e0 = (b - nb0 - nb1) * 4096; emax = N0_C; shift = 5; cap = CAPD; nbins = NB1_C;
        }
        const int mask = (1 << shift) - 1;
        for (int i = t; i < 512; i += 256) lcnt[i] = 0;
        __syncthreads();
        int lrank[16], dloc[16];
        #pragma unroll
        for (int i = 0; i < 16; ++i) {
            int e = e0 + t + i * 256;
            if (e < emax) {
                int d = dstp[e];
                dloc[i] = d;
                lrank[i] = atomicAdd(&lcnt[d >> shift], 1);
            } else dloc[i] = -1;
        }
        __syncthreads();
        for (int i = t; i < nbins; i += 256)
            if (lcnt[i] > 0) sbase[i] = atomicAdd(&bc[i], lcnt[i]);
        __syncthreads();
        #pragma unroll
        for (int i = 0; i < 16; ++i) {
            int e = e0 + t + i * 256;
            if (e < emax) {
                int d = dloc[i];
                int bin = d >> shift;
                int key = ((d & mask) << 17) | srcp[e];
                pr[(size_t)bin * cap + sbase[bin] + lrank[i]] = key;
            }
        }
        return;
    }
    // ---- layer-0 dual GEMM (swapped operands; next-tile A prefetch) ----
    const int gstride = gridDim.x - nscat;
    const int bid = b - nscat;
    const int wave = t >> 6, lane = t & 63;
    const int m = lane & 15, quad = lane >> 4;
    const int colbase = wave * 32;
    bf16x8 bf[4][2][2];
    #pragma unroll
    for (int c = 0; c < 4; ++c)
        #pragma unroll
        for (int ct = 0; ct < 2; ++ct) {
            const size_t bo = (size_t)(colbase + ct * 16 + m) * 128 + c * 32 + quad * 8;
            bf[c][ct][0] = *(const bf16x8*)(w1 + bo);
            bf[c][ct][1] = *(const bf16x8*)(w2 + bo);
        }
    const f32x4 zero = {0.f, 0.f, 0.f, 0.f};
    float4 pa0[4], pa1[4];
    auto ldA = [&](int tile) {
        const int r0 = tile * 16;
        int ar = r0 + m; if (ar >= N) ar = N - 1;
        const float* arow = A + (size_t)ar * 128;
        #pragma unroll
        for (int c = 0; c < 4; ++c) {
            pa0[c] = *(const float4*)(arow + c * 32 + quad * 8);
            pa1[c] = *(const float4*)(arow + c * 32 + quad * 8 + 4);
        }
    };
    if (bid < ntiles) ldA(bid);
    for (int tile = bid; tile < ntiles; tile += gstride) {
        float4 ca0[4], ca1[4];
        #pragma unroll
        for (int c = 0; c < 4; ++c) { ca0[c] = pa0[c]; ca1[c] = pa1[c]; }
        const int nxt = tile + gstride;
        if (nxt < ntiles) ldA(nxt);          // issue next-tile loads early
        f32x4 acc[2][2];
        acc[0][0] = zero; acc[0][1] = zero; acc[1][0] = zero; acc[1][1] = zero;
        #pragma unroll
        for (int c = 0; c < 4; ++c) {
            float av[8] = {ca0[c].x, ca0[c].y, ca0[c].z, ca0[c].w,
                           ca1[c].x, ca1[c].y, ca1[c].z, ca1[c].w};
            bf16x8 afh, afl;
            #pragma unroll
            for (int i = 0; i < 8; ++i) {
                ushort h = f2bf_rne(av[i]);
                ushort l = f2bf_rne(av[i] - bf2f(h));
                afh[i] = (short)h; afl[i] = (short)l;
            }
            #pragma unroll
            for (int ct = 0; ct < 2; ++ct) {
                acc[ct][0] = __builtin_amdgcn_mfma_f32_16x16x32_bf16(bf[c][ct][0], afh, acc[ct][0], 0, 0, 0);
                acc[ct][0] = __builtin_amdgcn_mfma_f32_16x16x32_bf16(bf[c][ct][0], afl, acc[ct][0], 0, 0, 0);
                acc[ct][1] = __builtin_amdgcn_mfma_f32_16x16x32_bf16(bf[c][ct][1], afh, acc[ct][1], 0, 0, 0);
                acc[ct][1] = __builtin_amdgcn_mfma_f32_16x16x32_bf16(bf[c][ct][1], afl, acc[ct][1], 0, 0, 0);
            }
        }
        const int r = tile * 16 + m;
        #pragma unroll
        for (int ct = 0; ct < 2; ++ct) {
            const int wc = colbase + ct * 16 + quad * 4;
            float4 bv = bias1 ? *(const float4*)&bias1[wc] : make_float4(0.f, 0.f, 0.f, 0.f);
            float o1[4], o2[4];
            o1[0] = acc[ct][0][0] + bv.x; o1[1] = acc[ct][0][1] + bv.y;
            o1[2] = acc[ct][0][2] + bv.z; o1[3] = acc[ct][0][3] + bv.w;
            o2[0] = acc[ct][1][0]; o2[1] = acc[ct][1][1];
            o2[2] = acc[ct][1][2]; o2[3] = acc[ct][1][3];
            if (r < N) {
                uint2 u;
                u.x = (uint)f2bf_rne(o1[0]) | ((uint)f2bf_rne(o1[1]) << 16);
                u.y = (uint)f2bf_rne(o1[2]) | ((uint)f2bf_rne(o1[3]) << 16);
                *(uint2*)&O1b[(size_t)r * D_DIM + wc] = u;
                int pk = __builtin_amdgcn_cvt_pk_fp8_f32(o2[0], o2[1], 0, false);
                pk = __builtin_amdgcn_cvt_pk_fp8_f32(o2[2], o2[3], pk, true);
                *(uint*)&O2f8[(size_t)r * D_DIM + wc] = (uint)pk;
            }
        }
    }
}

// ---------------------------------------------------------------------------
// sortbins: one block per bin (all three edge sets). In-LDS rank + scan ->
// sorted colv written back to GLOBAL (coalesced) + per-dst beg/end arrays.
// ---------------------------------------------------------------------------
__global__ __launch_bounds__(256) void sortbins_kernel(
    const int* __restrict__ pairs0, const int* __restrict__ bincur0,
    const int* __restrict__ pairs1, const int* __restrict__ bincur1,
    const int* __restrict__ pairsD, const int* __restrict__ bincurD,
    int* __restrict__ col0, int* __restrict__ beg0, int* __restrict__ end0,
    int* __restrict__ col1, int* __restrict__ beg1, int* __restrict__ end1,
    int* __restrict__ colD, int* __restrict__ begD, int* __restrict__ endD) {
    __shared__ int cols[CAP0];
    __shared__ int cur[128];
    __shared__ int wtot_s;
    const int tid = threadIdx.x;
    int b = blockIdx.x;
    const int* pr; const int* bc; int* cg; int* bg; int* eg;
    int cap, nloc, nbase, nmax;
    if (b < NB0_C) {
        pr = pairs0; bc = bincur0; cg = col0; bg = beg0; eg = end0;
        cap = CAP0; nloc = 128; nbase = b << 7; nmax = N0_C;
    } else if (b < NB0_C + NB1_C) {
        b -= NB0_C;
        pr = pairs1; bc = bincur1; cg = col1; bg = beg1; eg = end1;
        cap = CAP1; nloc = 32; nbase = b << 5; nmax = N1_C;
    } else {
        b -= NB0_C + NB1_C;
        pr = pairsD; bc = bincurD; cg = colD; bg = begD; eg = endD;
        cap = CAPD; nloc = 32; nbase = b << 5; nmax = N1_C;
    }
    const size_t base = (size_t)b * cap;
    int cnt = bc[b]; if (cnt > cap) cnt = cap;
    if (tid < 128) cur[tid] = 0;
    __syncthreads();
    int key[10], rank[10];
    #pragma unroll
    for (int k = 0; k < 10; ++k) {
        int idx = tid + k * 256;
        key[k] = (idx < cnt) ? pr[base + idx] : -1;
    }
    #pragma unroll
    for (int k = 0; k < 10; ++k)
        if (key[k] >= 0) rank[k] = atomicAdd(&cur[key[k] >> 17], 1);
    __syncthreads();
    __shared__ int rp[129];
    int v = 0, x = 0;
    if (tid < 128) {
        v = cur[tid];
        x = v;
        int lane = tid & 63;
        #pragma unroll
        for (int off = 1; off < 64; off <<= 1) {
            int y = __shfl_up(x, off);
            if (lane >= off) x += y;
        }
        if (tid == 63) wtot_s = x;
    }
    __syncthreads();
    if (tid < 128) {
        int excl = x - v + ((tid >= 64) ? wtot_s : 0);
        rp[tid] = excl;
        if (tid == 127) rp[128] = excl + v;
        if (tid < nloc) {
            int n = nbase + tid;
            if (n < nmax) {
                bg[n] = (int)base + excl;
                eg[n] = (int)base + excl + v;
            }
        }
    }
    __syncthreads();
    #pragma unroll
    for (int k = 0; k < 10; ++k)
        if (key[k] >= 0)
            cols[rp[key[k] >> 17] + rank[k]] = key[k] & 0x1FFFF;
    __syncthreads();
    for (int i = tid; i < cnt; i += 256) cg[base + i] = cols[i];
}

// ---------------------------------------------------------------------------
// big CSR gather-aggregate, 2 nodes/wave; FP8 (128B rows) or bf16 (256B rows).
// Optional bf16 addvb OR f32 addvf; out bf16 outb OR f32 outf OR fused
// readout z = (...)@Wm + bm with per-block online-softmax partial to redp
// (requires exact grid: every block fully populated).
// ---------------------------------------------------------------------------
template <int FP8>
__global__ __launch_bounds__(256) void csr_agg_big(
    const void* __restrict__ featv,
    const int* __restrict__ rpbeg, const int* __restrict__ rpend,
    const int* __restrict__ colv,
    const ushort* __restrict__ addvb, const float* __restrict__ addvf,
    const float* __restrict__ bias,
    ushort* __restrict__ outb, float* __restrict__ outf,
    const float* __restrict__ Wm, const float* __restrict__ bm,
    float* __restrict__ z, float* __restrict__ redp, int Ndst, int do_relu) {
    __shared__ float zsh[8];
    const char* feat = (const char*)featv;
    int gt = blockIdx.x * blockDim.x + threadIdx.x;
    int wp = gt >> 6;
    int nA = wp * 2;
    if (nA >= Ndst) return;
    int nB = nA + 1;
    bool hasB = (nB < Ndst);
    int lane = threadIdx.x & 63;
    int q = lane >> 4, li = lane & 15;
    float accA[8], accB[8];
    #pragma unroll
    for (int i = 0; i < 8; ++i) { accA[i] = 0.f; accB[i] = 0.f; }
    int begA = rpbeg[nA], endA = rpend[nA];
    int begB = 0, endB = 0;
    if (hasB) { begB = rpbeg[nB]; endB = rpend[nB]; }
    int degA = endA - begA, degB = endB - begB;
    int lastA = (degA > 0) ? endA - 1 : 0;
    int lastB = (degB > 0) ? endB - 1 : 0;
    int jA = begA + q, jB = begB + q;
    while (jA < endA || jB < endB) {
        int ia[4], ib[4];
        #pragma unroll
        for (int k = 0; k < 4; ++k) {
            ia[k] = imin(jA + 4 * k, lastA);
            ib[k] = imin(jB + 4 * k, lastB);
        }
        if (FP8) {
            uint2 va[4], vb[4];
            #pragma unroll
            for (int k = 0; k < 4; ++k) {
                int ra = colv[ia[k]];
                va[k] = *(const uint2*)(feat + (size_t)ra * 128 + li * 8);
            }
            #pragma unroll
            for (int k = 0; k < 4; ++k) {
                int rb = colv[ib[k]];
                vb[k] = *(const uint2*)(feat + (size_t)rb * 128 + li * 8);
            }
            #pragma unroll
            for (int k = 0; k < 4; ++k) {
                if (jA + 4 * k < endA) acc8_add_f8(accA, va[k]);
                if (jB + 4 * k < endB) acc8_add_f8(accB, vb[k]);
            }
        } else {
            uint4 va[4], vb[4];
            #pragma unroll
            for (int k = 0; k < 4; ++k) {
                int ra = colv[ia[k]];
                va[k] = *(const uint4*)(feat + (size_t)ra * 256 + li * 16);
            }
            #pragma unroll
            for (int k = 0; k < 4; ++k) {
                int rb = colv[ib[k]];
                vb[k] = *(const uint4*)(feat + (size_t)rb * 256 + li * 16);
            }
            #pragma unroll
            for (int k = 0; k < 4; ++k) {
                if (jA + 4 * k < endA) acc8_add_bf(accA, va[k]);
                if (jB + 4 * k < endB) acc8_add_bf(accB, vb[k]);
            }
        }
        jA += 16; jB += 16;
    }
    const int f8 = li * 8;
    #pragma unroll
    for (int i = 0; i < 8; ++i) {
        accA[i] += __shfl_xor(accA[i], 16);
        accA[i] += __shfl_xor(accA[i], 32);
        accB[i] += __shfl_xor(accB[i], 16);
        accB[i] += __shfl_xor(accB[i], 32);
    }
    float invA = 1.f / fmaxf((float)degA, 1.f);
    float invB = 1.f / fmaxf((float)degB, 1.f);
    #pragma unroll
    for (int i = 0; i < 8; ++i) { accA[i] *= invA; accB[i] *= invB; }
    if (addvb) {
        uint4 a = *(const uint4*)&addvb[(size_t)nA * D_DIM + f8];
        acc8_add_bf(accA, a);
        if (hasB) {
            uint4 b = *(const uint4*)&addvb[(size_t)nB * D_DIM + f8];
            acc8_add_bf(accB, b);
        }
    }
    if (addvf) {
        float4 g0 = *(const float4*)&addvf[(size_t)nA * D_DIM + f8];
        float4 g1 = *(const float4*)&addvf[(size_t)nA * D_DIM + f8 + 4];
        accA[0] += g0.x; accA[1] += g0.y; accA[2] += g0.z; accA[3] += g0.w;
        accA[4] += g1.x; accA[5] += g1.y; accA[6] += g1.z; accA[7] += g1.w;
        if (hasB) {
            float4 h0 = *(const float4*)&addvf[(size_t)nB * D_DIM + f8];
            float4 h1 = *(const float4*)&addvf[(size_t)nB * D_DIM + f8 + 4];
            accB[0] += h0.x; accB[1] += h0.y; accB[2] += h0.z; accB[3] += h0.w;
            accB[4] += h1.x; accB[5] += h1.y; accB[6] += h1.z; accB[7] += h1.w;
        }
    }
    if (bias) {
        float4 b0 = *(const float4*)&bias[f8];
        float4 b1 = *(const float4*)&bias[f8 + 4];
        accA[0] += b0.x; accA[1] += b0.y; accA[2] += b0.z; accA[3] += b0.w;
        accA[4] += b1.x; accA[5] += b1.y; accA[6] += b1.z; accA[7] += b1.w;
        accB[0] += b0.x; accB[1] += b0.y; accB[2] += b0.z; accB[3] += b0.w;
        accB[4] += b1.x; accB[5] += b1.y; accB[6] += b1.z; accB[7] += b1.w;
    }
    if (do_relu) {
        #pragma unroll
        for (int i = 0; i < 8; ++i) {
            accA[i] = fmaxf(accA[i], 0.f);
            accB[i] = fmaxf(accB[i], 0.f);
        }
    }
    if (outb) {
        if (q == 0) {
            uint4 o;
            o.x = (uint)f2bf_rne(accA[0]) | ((uint)f2bf_rne(accA[1]) << 16);
            o.y = (uint)f2bf_rne(accA[2]) | ((uint)f2bf_rne(accA[3]) << 16);
            o.z = (uint)f2bf_rne(accA[4]) | ((uint)f2bf_rne(accA[5]) << 16);
            o.w = (uint)f2bf_rne(accA[6]) | ((uint)f2bf_rne(accA[7]) << 16);
            *(uint4*)&outb[(size_t)nA * D_DIM + f8] = o;
        } else if (q == 1 && hasB) {
            uint4 o;
            o.x = (uint)f2bf_rne(accB[0]) | ((uint)f2bf_rne(accB[1]) << 16);
            o.y = (uint)f2bf_rne(accB[2]) | ((uint)f2bf_rne(accB[3]) << 16);
            o.z = (uint)f2bf_rne(accB[4]) | ((uint)f2bf_rne(accB[5]) << 16);
            o.w = (uint)f2bf_rne(accB[6]) | ((uint)f2bf_rne(accB[7]) << 16);
            *(uint4*)&outb[(size_t)nB * D_DIM + f8] = o;
        }
    } else if (outf) {
        if (q == 0) {
            float4 s0, s1;
            s0.x = accA[0]; s0.y = accA[1]; s0.z = accA[2]; s0.w = accA[3];
            s1.x = accA[4]; s1.y = accA[5]; s1.z = accA[6]; s1.w = accA[7];
            *(float4*)&outf[(size_t)nA * D_DIM + f8] = s0;
            *(float4*)&outf[(size_t)nA * D_DIM + f8 + 4] = s1;
        } else if (q == 1 && hasB) {
            float4 s0, s1;
            s0.x = accB[0]; s0.y = accB[1]; s0.z = accB[2]; s0.w = accB[3];
            s1.x = accB[4]; s1.y = accB[5]; s1.z = accB[6]; s1.w = accB[7];
            *(float4*)&outf[(size_t)nB * D_DIM + f8] = s0;
            *(float4*)&outf[(size_t)nB * D_DIM + f8 + 4] = s1;
        }
    }
    if (z) {
        float4 w0 = *(const float4*)&Wm[f8];
        float4 w1 = *(const float4*)&Wm[f8 + 4];
        float p = 0.f;
        if (q == 0)
            p = accA[0] * w0.x + accA[1] * w0.y + accA[2] * w0.z + accA[3] * w0.w
              + accA[4] * w1.x + accA[5] * w1.y + accA[6] * w1.z + accA[7] * w1.w;
        else if (q == 1)
            p = accB[0] * w0.x + accB[1] * w0.y + accB[2] * w0.z + accB[3] * w0.w
              + accB[4] * w1.x + accB[5] * w1.y + accB[6] * w1.z + accB[7] * w1.w;
        #pragma unroll
        for (int off = 8; off > 0; off >>= 1) p += __shfl_down(p, off);
        const int wv = threadIdx.x >> 6;
        if (lane == 0) {
            float zv = p + bm[0];
            z[nA] = zv;
            if (redp) zsh[2 * wv] = zv;
        }
        if (lane == 16 && hasB) {
            float zv = p + bm[0];
            z[nB] = zv;
            if (redp) zsh[2 * wv + 1] = zv;
        }
        if (redp) {
            __syncthreads();
            if (threadIdx.x == 0) {
                float m = -1e30f, s = 0.f;
                #pragma unroll
                for (int i = 0; i < 8; ++i) {
                    float v = zsh[i];
                    if (v > m) { s = s * __expf(m - v) + 1.f; m = v; }
                    else s += __expf(v - m);
                }
                redp[2 * blockIdx.x] = m;
                redp[2 * blockIdx.x + 1] = s;
            }
        }
    }
}

// ---------------------------------------------------------------------------
// fuseA: down-pool gather (16 nodes -> LDS bf16 tile) + layer-1 dual GEMM.
// One block per 16-row tile (nt1 blocks). x1 never hits global memory.
// LDS row stride 136 bf16 (+16B pad) -> 2-way bank alias only (free).
// ---------------------------------------------------------------------------
__global__ __launch_bounds__(256, 2) void fuseA_kernel(
    const ushort* __restrict__ x0b,
    const int* __restrict__ rpbeg, const int* __restrict__ rpend,
    const int* __restrict__ colv,
    const ushort* __restrict__ w1, const ushort* __restrict__ w2,
    const float* __restrict__ bias1,
    float* __restrict__ O1f, ushort* __restrict__ O2bb, int N) {
    __shared__ ushort As[16][136];
    const int tid = threadIdx.x;
    const int wave = tid >> 6, lane = tid & 63;
    const int q = lane >> 4, li = lane & 15;
    const int f8 = li * 8;
    const int r0 = blockIdx.x * 16;
    // ---- gather phase: x1 = relu(mean_cluster(x0)), 2 node-pairs per wave ----
    #pragma unroll
    for (int t = 0; t < 2; ++t) {
        const int la = wave * 2 + t * 8;
        const int nA = r0 + la, nB = nA + 1;
        float accA[8], accB[8];
        #pragma unroll
        for (int i = 0; i < 8; ++i) { accA[i] = 0.f; accB[i] = 0.f; }
        int begA = (nA < N) ? rpbeg[nA] : 0, endA = (nA < N) ? rpend[nA] : 0;
        int begB = (nB < N) ? rpbeg[nB] : 0, endB = (nB < N) ? rpend[nB] : 0;
        int degA = endA - begA, degB = endB - begB;
        int lastA = (degA > 0) ? endA - 1 : 0;
        int lastB = (degB > 0) ? endB - 1 : 0;
        int jA = begA + q, jB = begB + q;
        while (jA < endA || jB < endB) {
            int ia[4], ib[4];
            #pragma unroll
            for (int k = 0; k < 4; ++k) {
                ia[k] = imin(jA + 4 * k, lastA);
                ib[k] = imin(jB + 4 * k, lastB);
            }
            uint4 va[4], vb[4];
            #pragma unroll
            for (int k = 0; k < 4; ++k) {
                int ra = colv[ia[k]];
                va[k] = *(const uint4*)(x0b + (size_t)ra * D_DIM + f8);
            }
            #pragma unroll
            for (int k = 0; k < 4; ++k) {
                int rb = colv[ib[k]];
                vb[k] = *(const uint4*)(x0b + (size_t)rb * D_DIM + f8);
            }
            #pragma unroll
            for (int k = 0; k < 4; ++k) {
                if (jA + 4 * k < endA) acc8_add_bf(accA, va[k]);
                if (jB + 4 * k < endB) acc8_add_bf(accB, vb[k]);
            }
            jA += 16; jB += 16;
        }
        #pragma unroll
        for (int i = 0; i < 8; ++i) {
            accA[i] += __shfl_xor(accA[i], 16);
            accA[i] += __shfl_xor(accA[i], 32);
            accB[i] += __shfl_xor(accB[i], 16);
            accB[i] += __shfl_xor(accB[i], 32);
        }
        float invA = 1.f / fmaxf((float)degA, 1.f);
        float invB = 1.f / fmaxf((float)degB, 1.f);
        #pragma unroll
        for (int i = 0; i < 8; ++i) {
            accA[i] = fmaxf(accA[i] * invA, 0.f);
            accB[i] = fmaxf(accB[i] * invB, 0.f);
        }
        if (q == 0) {
            uint4 o;
            o.x = (uint)f2bf_rne(accA[0]) | ((uint)f2bf_rne(accA[1]) << 16);
            o.y = (uint)f2bf_rne(accA[2]) | ((uint)f2bf_rne(accA[3]) << 16);
            o.z = (uint)f2bf_rne(accA[4]) | ((uint)f2bf_rne(accA[5]) << 16);
            o.w = (uint)f2bf_rne(accA[6]) | ((uint)f2bf_rne(accA[7]) << 16);
            *(uint4*)&As[la][f8] = o;
        } else if (q == 1) {
            uint4 o;
            o.x = (uint)f2bf_rne(accB[0]) | ((uint)f2bf_rne(accB[1]) << 16);
            o.y = (uint)f2bf_rne(accB[2]) | ((uint)f2bf_rne(accB[3]) << 16);
            o.z = (uint)f2bf_rne(accB[4]) | ((uint)f2bf_rne(accB[5]) << 16);
            o.w = (uint)f2bf_rne(accB[6]) | ((uint)f2bf_rne(accB[7]) << 16);
            *(uint4*)&As[la + 1][f8] = o;
        }
    }
    __syncthreads();
    // ---- mm phase: y1s = x1@W1s + b1 (f32), y1n = x1@W1n (bf16) ----
    const int m = li, quad = q;
    const int colbase = wave * 32;
    bf16x8 bf[4][2][2];
    #pragma unroll
    for (int c = 0; c < 4; ++c)
        #pragma unroll
        for (int ct = 0; ct < 2; ++ct) {
            const size_t bo = (size_t)(colbase + ct * 16 + m) * 128 + c * 32 + quad * 8;
            bf[c][ct][0] = *(const bf16x8*)(w1 + bo);
            bf[c][ct][1] = *(const bf16x8*)(w2 + bo);
        }
    const f32x4 zero = {0.f, 0.f, 0.f, 0.f};
    f32x4 acc[2][2];
    acc[0][0] = zero; acc[0][1] = zero; acc[1][0] = zero; acc[1][1] = zero;
    #pragma unroll
    for (int c = 0; c < 4; ++c) {
        bf16x8 af = *(const bf16x8*)&As[m][c * 32 + quad * 8];
        #pragma unroll
        for (int ct = 0; ct < 2; ++ct) {
            acc[ct][0] = __builtin_amdgcn_mfma_f32_16x16x32_bf16(bf[c][ct][0], af, acc[ct][0], 0, 0, 0);
            acc[ct][1] = __builtin_amdgcn_mfma_f32_16x16x32_bf16(bf[c][ct][1], af, acc[ct][1], 0, 0, 0);
        }
    }
    const int r = r0 + m;
    if (r < N) {
        #pragma unroll
        for (int ct = 0; ct < 2; ++ct) {
            const int wc = colbase + ct * 16 + quad * 4;
            float4 bv = *(const float4*)&bias1[wc];
            float4 s1;
            s1.x = acc[ct][0][0] + bv.x; s1.y = acc[ct][0][1] + bv.y;
            s1.z = acc[ct][0][2] + bv.z; s1.w = acc[ct][0][3] + bv.w;
            *(float4*)&O1f[(size_t)r * D_DIM + wc] = s1;
            uint2 u;
            u.x = (uint)f2bf_rne(acc[ct][1][0]) | ((uint)f2bf_rne(acc[ct][1][1]) << 16);
            u.y = (uint)f2bf_rne(acc[ct][1][2]) | ((uint)f2bf_rne(acc[ct][1][3]) << 16);
            *(uint2*)&O2bb[(size_t)r * D_DIM + wc] = u;
        }
    }
}

// ---------------------------------------------------------------------------
// fuseB: graph1 gather x1f = relu(y1s + mean_nbr(y1n)) (16 nodes -> LDS f32
// tile) + layer-2 small dual GEMM (fp32 hi/lo). C2/D2 out. x1f never global.
// LDS row stride 132 f32 (+16B pad).
// ---------------------------------------------------------------------------
__global__ __launch_bounds__(256, 2) void fuseB_kernel(
    const ushort* __restrict__ y1nb,
    const int* __restrict__ rpbeg, const int* __restrict__ rpend,
    const int* __restrict__ colv, const float* __restrict__ y1sf,
    const ushort* __restrict__ w1, const ushort* __restrict__ w2,
    float* __restrict__ O1f, float* __restrict__ O2f, int N) {
    __shared__ float Bs[16][132];
    const int tid = threadIdx.x;
    const int wave = tid >> 6, lane = tid & 63;
    const int q = lane >> 4, li = lane & 15;
    const int f8 = li * 8;
    const int r0 = blockIdx.x * 16;
    #pragma unroll
    for (int t = 0; t < 2; ++t) {
        const int la = wave * 2 + t * 8;
        const int nA = r0 + la, nB = nA + 1;
        float accA[8], accB[8];
        #pragma unroll
        for (int i = 0; i < 8; ++i) { accA[i] = 0.f; accB[i] = 0.f; }
        int begA = (nA < N) ? rpbeg[nA] : 0, endA = (nA < N) ? rpend[nA] : 0;
        int begB = (nB < N) ? rpbeg[nB] : 0, endB = (nB < N) ? rpend[nB] : 0;
        int degA = endA - begA, degB = endB - begB;
        int lastA = (degA > 0) ? endA - 1 : 0;
        int lastB = (degB > 0) ? endB - 1 : 0;
        int jA = begA + q, jB = begB + q;
        while (jA < endA || jB < endB) {
            int ia[4], ib[4];
            #pragma unroll
            for (int k = 0; k < 4; ++k) {
                ia[k] = imin(jA + 4 * k, lastA);
                ib[k] = imin(jB + 4 * k, lastB);
            }
            uint4 va[4], vb[4];
            #pragma unroll
            for (int k = 0; k < 4; ++k) {
                int ra = colv[ia[k]];
                va[k] = *(const uint4*)(y1nb + (size_t)ra * D_DIM + f8);
            }
            #pragma unroll
            for (int k = 0; k < 4; ++k) {
                int rb = colv[ib[k]];
                vb[k] = *(const uint4*)(y1nb + (size_t)rb * D_DIM + f8);
            }
            #pragma unroll
            for (int k = 0; k < 4; ++k) {
                if (jA + 4 * k < endA) acc8_add_bf(accA, va[k]);
                if (jB + 4 * k < endB) acc8_add_bf(accB, vb[k]);
            }
            jA += 16; jB += 16;
        }
        #pragma unroll
        for (int i = 0; i < 8; ++i) {
            accA[i] += __shfl_xor(accA[i], 16);
            accA[i] += __shfl_xor(accA[i], 32);
            accB[i] += __shfl_xor(accB[i], 16);
            accB[i] += __shfl_xor(accB[i], 32);
        }
        float invA = 1.f / fmaxf((float)degA, 1.f);
        float invB = 1.f / fmaxf((float)degB, 1.f);
        #pragma unroll
        for (int i = 0; i < 8; ++i) { accA[i] *= invA; accB[i] *= invB; }
        if (nA < N) {
            float4 g0 = *(const float4*)&y1sf[(size_t)nA * D_DIM + f8];
            float4 g1 = *(const float4*)&y1sf[(size_t)nA * D_DIM + f8 + 4];
            accA[0] += g0.x; accA[1] += g0.y; accA[2] += g0.z; accA[3] += g0.w;
            accA[4] += g1.x; accA[5] += g1.y; accA[6] += g1.z; accA[7] += g1.w;
        }
        if (nB < N) {
            float4 h0 = *(const float4*)&y1sf[(size_t)nB * D_DIM + f8];
            float4 h1 = *(const float4*)&y1sf[(size_t)nB * D_DIM + f8 + 4];
            accB[0] += h0.x; accB[1] += h0.y; accB[2] += h0.z; accB[3] += h0.w;
            accB[4] += h1.x; accB[5] += h1.y; accB[6] += h1.z; accB[7] += h1.w;
        }
        #pragma unroll
        for (int i = 0; i < 8; ++i) {
            accA[i] = fmaxf(accA[i], 0.f);
            accB[i] = fmaxf(accB[i], 0.f);
        }
        if (q == 0) {
            float4 s0, s1;
            s0.x = accA[0]; s0.y = accA[1]; s0.z = accA[2]; s0.w = accA[3];
            s1.x = accA[4]; s1.y = accA[5]; s1.z = accA[6]; s1.w = accA[7];
            *(float4*)&Bs[la][f8] = s0;
            *(float4*)&Bs[la][f8 + 4] = s1;
        } else if (q == 1) {
            float4 s0, s1;
            s0.x = accB[0]; s0.y = accB[1]; s0.z = accB[2]; s0.w = accB[3];
            s1.x = accB[4]; s1.y = accB[5]; s1.z = accB[6]; s1.w = accB[7];
            *(float4*)&Bs[la + 1][f8] = s0;
            *(float4*)&Bs[la + 1][f8 + 4] = s1;
        }
    }
    __syncthreads();
    // ---- mm phase: C2 = x1f@W2s_top, D2 = x1f@W2n_top (fp32 hi/lo) ----
    const int m = li, quad = q;
    const int colbase = wave * 32;
    bf16x8 bf[4][2][2];
    #pragma unroll
    for (int c = 0; c < 4; ++c)
        #pragma unroll
        for (int ct = 0; ct < 2; ++ct) {
            const size_t bo = (size_t)(colbase + ct * 16 + m) * 128 + c * 32 + quad * 8;
            bf[c][ct][0] = *(const bf16x8*)(w1 + bo);
            bf[c][ct][1] = *(const bf16x8*)(w2 + bo);
        }
    const f32x4 zero = {0.f, 0.f, 0.f, 0.f};
    f32x4 acc[2][2];
    acc[0][0] = zero; acc[0][1] = zero; acc[1][0] = zero; acc[1][1] = zero;
    #pragma unroll
    for (int c = 0; c < 4; ++c) {
        float av[8];
        #pragma unroll
        for (int i = 0; i < 8; ++i) av[i] = Bs[m][c * 32 + quad * 8 + i];
        bf16x8 afh, afl;
        #pragma unroll
        for (int i = 0; i < 8; ++i) {
            ushort h = f2bf_rne(av[i]);
            ushort l = f2bf_rne(av[i] - bf2f(h));
            afh[i] = (short)h; afl[i] = (short)l;
        }
        #pragma unroll
        for (int ct = 0; ct < 2; ++ct) {
            acc[ct][0] = __builtin_amdgcn_mfma_f32_16x16x32_bf16(bf[c][ct][0], afh, acc[ct][0], 0, 0, 0);
            acc[ct][0] = __builtin_amdgcn_mfma_f32_16x16x32_bf16(bf[c][ct][0], afl, acc[ct][0], 0, 0, 0);
            acc[ct][1] = __builtin_amdgcn_mfma_f32_16x16x32_bf16(bf[c][ct][1], afh, acc[ct][1], 0, 0, 0);
            acc[ct][1] = __builtin_amdgcn_mfma_f32_16x16x32_bf16(bf[c][ct][1], afl, acc[ct][1], 0, 0, 0);
        }
    }
    const int r = r0 + m;
    if (r < N) {
        #pragma unroll
        for (int ct = 0; ct < 2; ++ct) {
            const int wc = colbase + ct * 16 + quad * 4;
            float4 s1, s2;
            s1.x = acc[ct][0][0]; s1.y = acc[ct][0][1];
            s1.z = acc[ct][0][2]; s1.w = acc[ct][0][3];
            s2.x = acc[ct][1][0]; s2.y = acc[ct][1][1];
            s2.z = acc[ct][1][2]; s2.w = acc[ct][1][3];
            *(float4*)&O1f[(size_t)r * D_DIM + wc] = s1;
            *(float4*)&O2f[(size_t)r * D_DIM + wc] = s2;
        }
    }
}

// bf16-A dual GEMM with next-tile A prefetch: bf16 O1 + fp8 O2 with ddst
// C2/D2 gather-add (layer-2 big).
__global__ __launch_bounds__(256, 2) void dualmm_regb_kernel(
    const ushort* __restrict__ Ab,
    const ushort* __restrict__ w1, const ushort* __restrict__ w2,
    const int* __restrict__ ddst,
    const float* __restrict__ C2g, const float* __restrict__ D2g,
    ushort* __restrict__ O1b, unsigned char* __restrict__ O2f8,
    int N, int ntiles) {
    const int tid = threadIdx.x;
    const int wave = tid >> 6, lane = tid & 63;
    const int m = lane & 15, quad = lane >> 4;
    const int colbase = wave * 32;
    bf16x8 bf[4][2][2];
    #pragma unroll
    for (int c = 0; c < 4; ++c)
        #pragma unroll
        for (int ct = 0; ct < 2; ++ct) {
            const size_t bo = (size_t)(colbase + ct * 16 + m) * 128 + c * 32 + quad * 8;
            bf[c][ct][0] = *(const bf16x8*)(w1 + bo);
            bf[c][ct][1] = *(const bf16x8*)(w2 + bo);
        }
    const f32x4 zero = {0.f, 0.f, 0.f, 0.f};
    bf16x8 pab[4];
    auto ldA = [&](int tile) {
        const int r0 = tile * 16;
        int ar = r0 + m; if (ar >= N) ar = N - 1;
        const ushort* arow = Ab + (size_t)ar * 128;
        #pragma unroll
        for (int c = 0; c < 4; ++c)
            pab[c] = *(const bf16x8*)(arow + c * 32 + quad * 8);
    };
    if ((int)blockIdx.x < ntiles) ldA(blockIdx.x);
    for (int tile = blockIdx.x; tile < ntiles; tile += gridDim.x) {
        bf16x8 ca[4];
        #pragma unroll
        for (int c = 0; c < 4; ++c) ca[c] = pab[c];
        const int nxt = tile + gridDim.x;
        if (nxt < ntiles) ldA(nxt);          // issue next-tile loads early
        f32x4 acc[2][2];
        acc[0][0] = zero; acc[0][1] = zero; acc[1][0] = zero; acc[1][1] = zero;
        #pragma unroll
        for (int c = 0; c < 4; ++c) {
            #pragma unroll
            for (int ct = 0; ct < 2; ++ct) {
                acc[ct][0] = __builtin_amdgcn_mfma_f32_16x16x32_bf16(bf[c][ct][0], ca[c], acc[ct][0], 0, 0, 0);
                acc[ct][1] = __builtin_amdgcn_mfma_f32_16x16x32_bf16(bf[c][ct][1], ca[c], acc[ct][1], 0, 0, 0);
            }
        }
        const int r = tile * 16 + m;
        const bool live = (r < N);
        int cc = live ? ddst[r] : 0;
        #pragma unroll
        for (int ct = 0; ct < 2; ++ct) {
            const int wc = colbase + ct * 16 + quad * 4;
            float4 g1 = make_float4(0.f, 0.f, 0.f, 0.f), g2 = g1;
            if (live) {
                g1 = *(const float4*)&C2g[(size_t)cc * D_DIM + wc];
                g2 = *(const float4*)&D2g[(size_t)cc * D_DIM + wc];
            }
            float o1[4], o2[4];
            o1[0] = acc[ct][0][0] + g1.x; o1[1] = acc[ct][0][1] + g1.y;
            o1[2] = acc[ct][0][2] + g1.z; o1[3] = acc[ct][0][3] + g1.w;
            o2[0] = acc[ct][1][0] + g2.x; o2[1] = acc[ct][1][1] + g2.y;
            o2[2] = acc[ct][1][2] + g2.z; o2[3] = acc[ct][1][3] + g2.w;
            if (live) {
                uint2 u;
                u.x = (uint)f2bf_rne(o1[0]) | ((uint)f2bf_rne(o1[1]) << 16);
                u.y = (uint)f2bf_rne(o1[2]) | ((uint)f2bf_rne(o1[3]) << 16);
                *(uint2*)&O1b[(size_t)r * D_DIM + wc] = u;
                int pk = __builtin_amdgcn_cvt_pk_fp8_f32(o2[0], o2[1], 0, false);
                pk = __builtin_amdgcn_cvt_pk_fp8_f32(o2[2], o2[3], pk, true);
                *(uint*)&O2f8[(size_t)r * D_DIM + wc] = (uint)pk;
            }
        }
    }
}

// ---------------------------------------------------------------------------
// softmax final: merge B per-block partials (written by readout gather),
// then write normalized output.
// ---------------------------------------------------------------------------
__global__ __launch_bounds__(256) void softmax_final_kernel(
    const float* __restrict__ z, const float* __restrict__ red,
    float* __restrict__ out, int N, int B) {
    __shared__ float sm[4], ss[4];
    __shared__ float sm_s, ss_s;
    int t = threadIdx.x, lane = t & 63, w = t >> 6;
    float m = -1e30f, s = 0.f;
    for (int i = t; i < B; i += 256) online2(m, s, red[2 * i], red[2 * i + 1]);
    #pragma unroll
    for (int off = 32; off > 0; off >>= 1) {
        float mo = __shfl_down(m, off), so = __shfl_down(s, off);
        online2(m, s, mo, so);
    }
    if (lane == 0) { sm[w] = m; ss[w] = s; }
    __syncthreads();
    if (t == 0) {
        for (int i = 1; i < 4; ++i) online2(m, s, sm[i], ss[i]);
        sm_s = m; ss_s = s;
    }
    __syncthreads();
    float mx = sm_s, sum = ss_s;
    for (int i = blockIdx.x * 256 + t; i < N; i += gridDim.x * 256)
        out[i] = expf(z[i] - mx) / sum;
}

// ---------------------------------------------------------------------------
// Host launcher
// ---------------------------------------------------------------------------
static inline char* align_up(char* p, size_t a) {
    return (char*)(((uintptr_t)p + a - 1) & ~(uintptr_t)(a - 1));
}

extern "C" void kernel_launch(void* const* d_in, const int* in_sizes, int n_in,
                              void* d_out, int out_size, void* d_ws, size_t ws_size,
                              hipStream_t stream) {
    const int N0 = N0_C, N1 = N1_C, E0 = E0_C, E1 = E1_C;
    const float* X   = (const float*)d_in[0];
    const float* W0s = (const float*)d_in[1];
    const float* W0n = (const float*)d_in[2];
    const float* b0  = (const float*)d_in[3];
    const float* W1s = (const float*)d_in[4];
    const float* W1n = (const float*)d_in[5];
    const float* b1  = (const float*)d_in[6];
    const float* W2s = (const float*)d_in[7];
    const float* W2n = (const float*)d_in[8];
    const float* b2  = (const float*)d_in[9];
    const float* Wm  = (const float*)d_in[10];
    const float* bm  = (const float*)d_in[11];
    const int* src0  = (const int*)d_in[12];
    const int* dst0  = (const int*)d_in[13];
    const int* src1  = (const int*)d_in[14];
    const int* dst1  = (const int*)d_in[15];
    const int* dsrc  = (const int*)d_in[16];
    const int* ddst  = (const int*)d_in[17];
    float* out = (float*)d_out;

    char* p = (char*)d_ws;
    const size_t FB = (size_t)N0 * D_DIM;
    const size_t SB = (size_t)N1 * D_DIM;
    auto grab_f = [&](size_t nf) { p = align_up(p, 256); float* r = (float*)p; p += nf * 4; return r; };
    auto grab_i = [&](size_t ni) { p = align_up(p, 256); int* r = (int*)p; p += ni * 4; return r; };
    auto grab_u = [&](size_t nu) { p = align_up(p, 256); ushort* r = (ushort*)p; p += nu * 2; return r; };
    auto grab_b = [&](size_t nb) { p = align_up(p, 256); unsigned char* r = (unsigned char*)p; p += nb; return r; };

    // zero-init region (zeroed by wtprep block 512): [bincur0 512 | bincur1 256 | bincurD 256]
    int* zeroRegion = grab_i(1024);
    int* bincur0 = zeroRegion;
    int* bincur1 = zeroRegion + 512;
    int* bincurD = zeroRegion + 768;

    float* y1s  = grab_f(SB);
    float* C2   = grab_f(SB);
    float* D2   = grab_f(SB);
    float* zbuf = grab_f(N0);
    float* red  = grab_f(2 * ((N0 + 7) / 8) + 32);
    ushort* y0sb = grab_u(FB);
    ushort* x0b  = grab_u(FB);
    ushort* y2sb = grab_u(FB);
    ushort* y1nb = grab_u(SB);
    unsigned char* y0nf8 = grab_b(FB);
    unsigned char* y2nf8 = grab_b(FB);
    ushort* wt   = grab_u(8 * 16384);
    int* pairs0 = grab_i((size_t)NB0_C * CAP0);
    int* pairs1 = grab_i((size_t)NB1_C * CAP1);
    int* pairsD = grab_i((size_t)NB1_C * CAPD);
    int* col0 = grab_i((size_t)NB0_C * CAP0);
    int* col1 = grab_i((size_t)NB1_C * CAP1);
    int* colD = grab_i((size_t)NB1_C * CAPD);
    int* beg0 = grab_i(N0); int* end0 = grab_i(N0);
    int* beg1 = grab_i(N1); int* end1 = grab_i(N1);
    int* begD = grab_i(N1); int* endD = grab_i(N1);
    (void)ws_size; (void)n_in; (void)in_sizes; (void)out_size;

    const int BT = 256;
    auto cdiv = [](int a, int b) { return (a + b - 1) / b; };
    auto WT = [&](int mi) { return wt + ((size_t)mi << 14); };
    const int nt0 = cdiv(N0, 16);
    const int nt1 = cdiv(N1, 16);
    const int nb0 = cdiv(E0, 4096);        // 196
    const int nb1 = cdiv(E1, 4096);        // 20
    const int nbd = cdiv(N0, 4096);        // 13
    const int G0 = 512;
    const int NBRO = cdiv(N0, 8);          // 6250 readout blocks (exact: 50000/8)

    // weights -> bf16 col-major  (+ block 512 zeros the counters)
    wtprep_kernel<<<513, BT, 0, stream>>>(W0s, W0n, W1s, W1n, W2s, W2n, wt, zeroRegion);

    // binned pair scatter (all 3 edge sets) + layer-0 dual GEMM, fused
    scatgemm_kernel<<<nb0 + nb1 + nbd + G0, BT, 0, stream>>>(
        src0, dst0, src1, dst1, dsrc, ddst,
        bincur0, bincur1, bincurD, pairs0, pairs1, pairsD,
        nb0, nb1, nbd,
        X, WT(0), WT(1), b0, y0sb, y0nf8, N0, nt0);

    // sort all bins -> global sorted colv + per-dst beg/end
    sortbins_kernel<<<NB0_C + 2 * NB1_C, BT, 0, stream>>>(
        pairs0, bincur0, pairs1, bincur1, pairsD, bincurD,
        col0, beg0, end0, col1, beg1, end1, colD, begD, endD);

    // x0 = y0s + mean_nbr(y0n)   (wide gather)
    csr_agg_big<1><<<NBRO, BT, 0, stream>>>(y0nf8, beg0, end0, col0,
        y0sb, nullptr, nullptr, x0b, nullptr, nullptr, nullptr, nullptr,
        nullptr, N0, 0);

    // fuseA: x1 = relu(mean_cluster(x0)) -> LDS -> y1s (f32,+b1), y1n (bf16)
    fuseA_kernel<<<nt1, BT, 0, stream>>>(x0b, begD, endD, colD,
        WT(2), WT(3), b1, y1s, y1nb, N1);

    // fuseB: x1f = relu(y1s + mean_nbr(y1n)) -> LDS -> C2, D2 (f32)
    fuseB_kernel<<<nt1, BT, 0, stream>>>(y1nb, beg1, end1, col1, y1s,
        WT(4), WT(6), C2, D2, N1);

    // layer 2 big: y2s = x0@W2s_bot + C2[ddst], y2n = x0@W2n_bot + D2[ddst]
    dualmm_regb_kernel<<<G0, BT, 0, stream>>>(x0b, WT(5), WT(7),
        ddst, C2, D2, y2sb, y2nf8, N0, nt0);

    // layer 2 combine + readout z + per-block softmax partials
    csr_agg_big<1><<<NBRO, BT, 0, stream>>>(y2nf8, beg0, end0, col0,
        y2sb, nullptr, b2, nullptr, nullptr, Wm, bm, zbuf, red, N0, 1);

    // softmax final: merge 6250 partials, write out
    softmax_final_kernel<<<128, BT, 0, stream>>>(zbuf, red, out, N0, NBRO);
}